// Round 2
// baseline (674.303 us; speedup 1.0000x reference)
//
#include <hip/hip_runtime.h>
#include <hip/hip_bf16.h>

// Problem constants (from reference setup_inputs)
#define BB    4
#define NTOT  16384
#define CC    256
#define HH    8
#define DD    64
#define HD    512
#define OUTC  256

typedef unsigned short u16;
typedef __attribute__((ext_vector_type(8))) short bf16x8;   // 8 bf16 in 4 VGPRs
typedef __attribute__((ext_vector_type(4))) float f32x4;

__device__ __forceinline__ float b2f(u16 u) {
    union { float f; unsigned int i; } x; x.i = ((unsigned int)u) << 16; return x.f;
}
__device__ __forceinline__ u16 f2b(float f) {
    union { float f; unsigned int i; } x; x.f = f;
    unsigned int r = x.i + 0x7fffu + ((x.i >> 16) & 1u);   // round-to-nearest-even
    return (u16)(r >> 16);
}

// ---------------------------------------------------------------------------
// fp32 -> bf16 conversion, 8 elements/thread. n must be a multiple of 8.
// ---------------------------------------------------------------------------
__global__ __launch_bounds__(256) void cvt_f32_bf16(
    const float* __restrict__ src, u16* __restrict__ dst, int n)
{
    const int i = (blockIdx.x * 256 + threadIdx.x) * 8;
    if (i >= n) return;
    const float4 a = *(const float4*)(src + i);
    const float4 b = *(const float4*)(src + i + 4);
    union { bf16x8 v; u16 s[8]; } o;
    o.s[0] = f2b(a.x); o.s[1] = f2b(a.y); o.s[2] = f2b(a.z); o.s[3] = f2b(a.w);
    o.s[4] = f2b(b.x); o.s[5] = f2b(b.y); o.s[6] = f2b(b.z); o.s[7] = f2b(b.w);
    *(bf16x8*)(dst + i) = o.v;
}

// ---------------------------------------------------------------------------
// C[m,n] = sum_k A[m,k] * Bm[n,k]  (+ bias[n]); A row-major [M,K] bf16, Bm
// row-major [Nm,K] bf16 (i.e. B^T input), C row-major [M,Nm] (bf16 or fp32).
// 128x128 tile, 4 waves. All dims multiples of tile sizes.
// ---------------------------------------------------------------------------
template <typename CT>
__global__ __launch_bounds__(256) void gemm_bt(
    const u16* __restrict__ A, const u16* __restrict__ Bm,
    CT* __restrict__ C, const float* __restrict__ bias,
    int M, int Nm, int K,
    long long aStride, long long bStride, long long cStride)
{
    const int bz = blockIdx.z;
    A  += (long long)bz * aStride;
    Bm += (long long)bz * bStride;
    C  += (long long)bz * cStride;

    const int m0 = blockIdx.x * 128;
    const int n0 = blockIdx.y * 128;
    const int wave = threadIdx.x >> 6;
    const int lane = threadIdx.x & 63;
    const int wy = wave >> 1, wx = wave & 1;
    const int r16  = lane & 15;   // row (A) / col (B) within a 16-tile
    const int quad = lane >> 4;   // k-octet selector / output row quad

    const int mBase = m0 + wy * 64 + r16;
    const int nBase = n0 + wx * 64 + r16;

    f32x4 acc[4][4] = {};

    for (int kk = 0; kk < K; kk += 32) {
        const int ka = kk + quad * 8;
        bf16x8 a[4], b[4];
#pragma unroll
        for (int i = 0; i < 4; i++)
            a[i] = *(const bf16x8*)(A + (long long)(mBase + 16 * i) * K + ka);
#pragma unroll
        for (int j = 0; j < 4; j++)
            b[j] = *(const bf16x8*)(Bm + (long long)(nBase + 16 * j) * K + ka);
#pragma unroll
        for (int i = 0; i < 4; i++)
#pragma unroll
            for (int j = 0; j < 4; j++)
                acc[i][j] = __builtin_amdgcn_mfma_f32_16x16x32_bf16(a[i], b[j], acc[i][j], 0, 0, 0);
    }

    // C/D layout: col = lane&15, row = quad*4 + reg
#pragma unroll
    for (int j = 0; j < 4; j++) {
        const int col = n0 + wx * 64 + 16 * j + r16;
        const float bv = bias ? bias[col] : 0.0f;
#pragma unroll
        for (int i = 0; i < 4; i++) {
#pragma unroll
            for (int r = 0; r < 4; r++) {
                const int row = m0 + wy * 64 + 16 * i + quad * 4 + r;
                const float v = acc[i][j][r] + bv;
                if constexpr (sizeof(CT) == 2) C[(long long)row * Nm + col] = f2b(v);
                else                           C[(long long)row * Nm + col] = v;
            }
        }
    }
}

// ---------------------------------------------------------------------------
// Per-column (b, c in [0,512)) partial sums / sumsq over an N-slice.
// grid: (8 cblk * 8 nsplit, B, 2{K,V}); statsP layout [w][b][ns][2][512]
// ---------------------------------------------------------------------------
__global__ __launch_bounds__(256) void stats_partial(
    const u16* __restrict__ Kb, const u16* __restrict__ Vb,
    float* __restrict__ statsP)
{
    const int cblk = blockIdx.x & 7;
    const int ns   = blockIdx.x >> 3;
    const int b    = blockIdx.y;
    const int w    = blockIdx.z;
    const u16* src = w ? Vb : Kb;

    const int tc = threadIdx.x & 63;
    const int tn = threadIdx.x >> 6;
    const int c  = cblk * 64 + tc;

    float s = 0.f, s2 = 0.f;
    const int nbase = ns * (NTOT / 8);
    for (int n = nbase + tn; n < nbase + NTOT / 8; n += 4) {
        float x = b2f(src[((long long)(b * NTOT + n)) * HD + c]);
        s += x; s2 += x * x;
    }
    __shared__ float ls[4][64], ls2[4][64];
    ls[tn][tc] = s; ls2[tn][tc] = s2;
    __syncthreads();
    if (tn == 0) {
        s  = ls[0][tc] + ls[1][tc] + ls[2][tc] + ls[3][tc];
        s2 = ls2[0][tc] + ls2[1][tc] + ls2[2][tc] + ls2[3][tc];
        float* p = statsP + (((w * BB + b) * 8 + ns) * 2) * (long long)HD;
        p[c]      = s;
        p[HD + c] = s2;
    }
}

// statsF layout [w][b][2][512]: mean then rstd
__global__ __launch_bounds__(512) void stats_final(
    const float* __restrict__ statsP, float* __restrict__ statsF)
{
    const int b = blockIdx.x, w = blockIdx.y;
    const int c = threadIdx.x;
    float s = 0.f, s2 = 0.f;
    for (int ns = 0; ns < 8; ns++) {
        const float* p = statsP + (((w * BB + b) * 8 + ns) * 2) * (long long)HD;
        s += p[c]; s2 += p[HD + c];
    }
    const float m   = s * (1.0f / NTOT);
    const float var = s2 * (1.0f / NTOT) - m * m;
    float* q = statsF + ((w * BB + b) * 2) * (long long)HD;
    q[c]      = m;
    q[HD + c] = rsqrtf(var + 1e-5f);
}

// ---------------------------------------------------------------------------
// S[b,h,d,e] += sum_{n in chunk} K[b,n,h*64+d] * V[b,n,h*64+e]  (raw, uncentered)
// grid: (32 bh, 16 chunks), 256 threads; each thread owns a 4x4 (d,e) block.
// ---------------------------------------------------------------------------
#define NCHUNK 16
__global__ __launch_bounds__(256) void kv_outer(
    const u16* __restrict__ Kb, const u16* __restrict__ Vb,
    float* __restrict__ S)
{
    const int bh = blockIdx.x;
    const int b = bh >> 3, h = bh & 7;
    const int chunk = blockIdx.y;
    const int CH = NTOT / NCHUNK;
    const int n0 = chunk * CH;

    __shared__ float lk[16][64];
    __shared__ float lv[16][64];

    const int t = threadIdx.x;
    const int d0 = (t >> 4) * 4;
    const int e0 = (t & 15) * 4;

    const int lrow = (t & 127) >> 3;  // 0..15
    const int lseg = t & 7;           // 0..7
    const bool isV = t >= 128;
    const u16* src = isV ? Vb : Kb;

    float acc[4][4] = {};

    for (int nn = n0; nn < n0 + CH; nn += 16) {
        bf16x8 raw = *(const bf16x8*)(src + ((long long)(b * NTOT + nn + lrow)) * HD + h * 64 + lseg * 8);
        float* dst = (isV ? &lv[lrow][lseg * 8] : &lk[lrow][lseg * 8]);
#pragma unroll
        for (int q = 0; q < 8; q++) dst[q] = b2f((u16)raw[q]);
        __syncthreads();
#pragma unroll
        for (int n = 0; n < 16; n++) {
            f32x4 kq = *(const f32x4*)&lk[n][d0];
            f32x4 vq = *(const f32x4*)&lv[n][e0];
#pragma unroll
            for (int i = 0; i < 4; i++)
#pragma unroll
                for (int j = 0; j < 4; j++)
                    acc[i][j] += kq[i] * vq[j];
        }
        __syncthreads();
    }

    float* Sp = S + (long long)bh * 4096;
#pragma unroll
    for (int i = 0; i < 4; i++)
#pragma unroll
        for (int j = 0; j < 4; j++)
            atomicAdd(&Sp[(d0 + i) * 64 + (e0 + j)], acc[i][j]);
}

// ---------------------------------------------------------------------------
// kv[d,e] = rk_d*rv_e*(S[d,e]/N - mk_d*mv_e);
// W2T[b,o,h*64+d] = sum_e kv[d,e]*Wo[o,h*64+e]   (Wo read in fp32)
// grid: 32 (bh), 256 threads (one per o).
// ---------------------------------------------------------------------------
__global__ __launch_bounds__(256) void combine(
    const float* __restrict__ S, const float* __restrict__ statsF,
    const float* __restrict__ Wo, u16* __restrict__ W2T)
{
    const int bh = blockIdx.x;
    const int b = bh >> 3, h = bh & 7;
    __shared__ float kv[64][64];
    const int t = threadIdx.x;

    const float* mk = statsF + ((0 * BB + b) * 2) * (long long)HD;  // mean; +HD = rstd
    const float* mv = statsF + ((1 * BB + b) * 2) * (long long)HD;
    const float* Sp = S + (long long)bh * 4096;

    for (int idx = t; idx < 4096; idx += 256) {
        const int d = idx >> 6, e = idx & 63;
        const int cd = h * 64 + d, ce = h * 64 + e;
        kv[d][e] = (Sp[idx] * (1.0f / NTOT) - mk[cd] * mv[ce]) * mk[HD + cd] * mv[HD + ce];
    }
    __syncthreads();

    const int o = t;  // 0..255
    float wo[64];
    const float* woP = Wo + (long long)o * HD + h * 64;
#pragma unroll
    for (int s4 = 0; s4 < 16; s4++) {
        f32x4 r = *(const f32x4*)(woP + s4 * 4);
        wo[s4 * 4]     = r[0]; wo[s4 * 4 + 1] = r[1];
        wo[s4 * 4 + 2] = r[2]; wo[s4 * 4 + 3] = r[3];
    }
    for (int d = 0; d < 64; d++) {
        float acc = 0.f;
        const f32x4* kvr = (const f32x4*)kv[d];
#pragma unroll
        for (int e4 = 0; e4 < 16; e4++) {
            f32x4 kq = kvr[e4];
            acc += kq[0] * wo[e4 * 4] + kq[1] * wo[e4 * 4 + 1]
                 + kq[2] * wo[e4 * 4 + 2] + kq[3] * wo[e4 * 4 + 3];
        }
        W2T[((long long)b * OUTC + o) * HD + h * 64 + d] = f2b(acc);
    }
}

// ---------------------------------------------------------------------------
extern "C" void kernel_launch(void* const* d_in, const int* in_sizes, int n_in,
                              void* d_out, int out_size, void* d_ws, size_t ws_size,
                              hipStream_t stream)
{
    const float* u_src = (const float*)d_in[0];
    // d_in[1] = pos_src (unused by reference)
    const float* Wq = (const float*)d_in[2];
    const float* Wk = (const float*)d_in[3];
    const float* Wv = (const float*)d_in[4];
    const float* Wo = (const float*)d_in[5];
    const float* bo = (const float*)d_in[6];
    float* out = (float*)d_out;

    char* ws = (char*)d_ws;
    size_t off = 0;
    u16* u_bf  = (u16*)(ws + off); off += 33554432;           // 16.7M bf16 = 32MB
    u16* Wq_b  = (u16*)(ws + off); off += 262144;             // 512x256 bf16
    u16* Wk_b  = (u16*)(ws + off); off += 262144;
    u16* Wv_b  = (u16*)(ws + off); off += 262144;
    u16* KQ    = (u16*)(ws + off); off += 67108864;           // [65536,512] bf16
    u16* V     = (u16*)(ws + off); off += 67108864;
    float* S   = (float*)(ws + off); off += 524288;           // [32][64][64] f32
    float* stP = (float*)(ws + off); off += 262144;
    float* stF = (float*)(ws + off); off += 32768;
    u16* W2T   = (u16*)(ws + off); off += 1048576;            // [4][256][512] bf16

    const dim3 blk(256);
    const int Mtot = BB * NTOT;  // 65536
    const int NU = BB * NTOT * CC;   // 16777216
    const int NW = HD * CC;          // 131072

    // fp32 -> bf16
    cvt_f32_bf16<<<dim3(NU / 2048), blk, 0, stream>>>(u_src, u_bf, NU);
    cvt_f32_bf16<<<dim3(NW / 2048), blk, 0, stream>>>(Wq, Wq_b, NW);
    cvt_f32_bf16<<<dim3(NW / 2048), blk, 0, stream>>>(Wk, Wk_b, NW);
    cvt_f32_bf16<<<dim3(NW / 2048), blk, 0, stream>>>(Wv, Wv_b, NW);

    // K, V projections: [65536,256] x [256,512] -> bf16
    gemm_bt<u16><<<dim3(Mtot / 128, HD / 128, 1), blk, 0, stream>>>(
        u_bf, Wk_b, KQ, nullptr, Mtot, HD, CC, 0, 0, 0);
    gemm_bt<u16><<<dim3(Mtot / 128, HD / 128, 1), blk, 0, stream>>>(
        u_bf, Wv_b, V, nullptr, Mtot, HD, CC, 0, 0, 0);

    // instance-norm stats (mean/rstd per (b, channel))
    stats_partial<<<dim3(64, BB, 2), blk, 0, stream>>>(KQ, V, stP);
    stats_final<<<dim3(BB, 2), dim3(512), 0, stream>>>(stP, stF);

    // raw S = K^T V per (b,h)
    hipMemsetAsync(S, 0, 524288, stream);
    kv_outer<<<dim3(BB * HH, NCHUNK), blk, 0, stream>>>(KQ, V, S);

    // kv + fold Wo -> W2T[b, o, c]
    combine<<<dim3(BB * HH), blk, 0, stream>>>(S, stF, Wo, W2T);

    // Q projection (reuse KQ buffer)
    gemm_bt<u16><<<dim3(Mtot / 128, HD / 128, 1), blk, 0, stream>>>(
        u_bf, Wq_b, KQ, nullptr, Mtot, HD, CC, 0, 0, 0);

    // out[b,n,o] = Q[b,n,:] . W2T[b,o,:] + bo[o]  -> fp32
    gemm_bt<float><<<dim3(NTOT / 128, OUTC / 128, BB), blk, 0, stream>>>(
        KQ, W2T, out, bo, NTOT, OUTC, HD,
        (long long)NTOT * HD, (long long)OUTC * HD, (long long)NTOT * OUTC);
}

// Round 3
// 450.537 us; speedup vs baseline: 1.4967x; 1.4967x over previous
//
#include <hip/hip_runtime.h>
#include <hip/hip_bf16.h>

// Problem constants (from reference setup_inputs)
#define BB    4
#define NTOT  16384
#define CC    256
#define HH    8
#define DD    64
#define HD    512
#define OUTC  256

typedef unsigned short u16;
typedef __attribute__((ext_vector_type(8))) short bf16x8;   // 8 bf16 in 4 VGPRs
typedef __attribute__((ext_vector_type(4))) float f32x4;

__device__ __forceinline__ float b2f(u16 u) {
    union { float f; unsigned int i; } x; x.i = ((unsigned int)u) << 16; return x.f;
}
__device__ __forceinline__ u16 f2b(float f) {
    union { float f; unsigned int i; } x; x.f = f;
    unsigned int r = x.i + 0x7fffu + ((x.i >> 16) & 1u);   // round-to-nearest-even
    return (u16)(r >> 16);
}

// ---------------------------------------------------------------------------
// fp32 -> bf16 conversion, 8 elements/thread. n must be a multiple of 8.
// ---------------------------------------------------------------------------
__global__ __launch_bounds__(256) void cvt_f32_bf16(
    const float* __restrict__ src, u16* __restrict__ dst, int n)
{
    const int i = (blockIdx.x * 256 + threadIdx.x) * 8;
    if (i >= n) return;
    const float4 a = *(const float4*)(src + i);
    const float4 b = *(const float4*)(src + i + 4);
    union { bf16x8 v; u16 s[8]; } o;
    o.s[0] = f2b(a.x); o.s[1] = f2b(a.y); o.s[2] = f2b(a.z); o.s[3] = f2b(a.w);
    o.s[4] = f2b(b.x); o.s[5] = f2b(b.y); o.s[6] = f2b(b.z); o.s[7] = f2b(b.w);
    *(bf16x8*)(dst + i) = o.v;
}

// ---------------------------------------------------------------------------
// C[m,n] = sum_k A[m,k] * Bm[n,k]  (+ bias[n]); A row-major [M,K] bf16 with
// row stride lda, Bm row-major [Nm,K] bf16 dense (B^T input), C row-major
// with row stride ldc (bf16 or fp32). 128x128 tile, 4 waves, m97-style LDS
// staging via global_load_lds width=16 (wave-uniform LDS base + lane*16).
// ---------------------------------------------------------------------------
template <typename CT>
__global__ __launch_bounds__(256) void gemm_bt(
    const u16* __restrict__ A, const u16* __restrict__ Bm,
    CT* __restrict__ C, const float* __restrict__ bias,
    int K, int lda, int ldc,
    long long aStride, long long bStride, long long cStride)
{
    __shared__ u16 As[128 * 32];
    __shared__ u16 Bs[128 * 32];

    const int bz = blockIdx.z;
    A  += (long long)bz * aStride;
    Bm += (long long)bz * bStride;
    C  += (long long)bz * cStride;

    const int m0 = blockIdx.x * 128;
    const int n0 = blockIdx.y * 128;
    const int t  = threadIdx.x;
    const int wv = t >> 6, l = t & 63;
    const int wy = wv >> 1, wx = wv & 1;
    const int r16  = l & 15;
    const int quad = l >> 4;

    // staging lane mapping: row = s*64 + wv*16 + (l>>2), col = (l&3)*8
    const int srow = wv * 16 + (l >> 2);
    const int scol = (l & 3) * 8;

    f32x4 acc[4][4] = {};

    for (int kk = 0; kk < K; kk += 32) {
#pragma unroll
        for (int s = 0; s < 2; s++) {
            const u16* ga = A + (long long)(m0 + s * 64 + srow) * lda + kk + scol;
            __builtin_amdgcn_global_load_lds(
                (const __attribute__((address_space(1))) void*)ga,
                (__attribute__((address_space(3))) void*)(As + s * 2048 + wv * 512),
                16, 0, 0);
            const u16* gb = Bm + (long long)(n0 + s * 64 + srow) * K + kk + scol;
            __builtin_amdgcn_global_load_lds(
                (const __attribute__((address_space(1))) void*)gb,
                (__attribute__((address_space(3))) void*)(Bs + s * 2048 + wv * 512),
                16, 0, 0);
        }
        __syncthreads();

        bf16x8 a[4], b[4];
#pragma unroll
        for (int i = 0; i < 4; i++)
            a[i] = *(const bf16x8*)(As + (wy * 64 + 16 * i + r16) * 32 + quad * 8);
#pragma unroll
        for (int j = 0; j < 4; j++)
            b[j] = *(const bf16x8*)(Bs + (wx * 64 + 16 * j + r16) * 32 + quad * 8);
#pragma unroll
        for (int i = 0; i < 4; i++)
#pragma unroll
            for (int j = 0; j < 4; j++)
                acc[i][j] = __builtin_amdgcn_mfma_f32_16x16x32_bf16(a[i], b[j], acc[i][j], 0, 0, 0);
        __syncthreads();
    }

    // C/D layout: col = lane&15, row = quad*4 + reg
#pragma unroll
    for (int j = 0; j < 4; j++) {
        const int col = n0 + wx * 64 + 16 * j + r16;
        const float bv = bias ? bias[col] : 0.0f;
#pragma unroll
        for (int i = 0; i < 4; i++) {
#pragma unroll
            for (int r = 0; r < 4; r++) {
                const int row = m0 + wy * 64 + 16 * i + quad * 4 + r;
                const float v = acc[i][j][r] + bv;
                if constexpr (sizeof(CT) == 2) C[(long long)row * ldc + col] = f2b(v);
                else                           C[(long long)row * ldc + col] = v;
            }
        }
    }
}

// ---------------------------------------------------------------------------
// Vectorized per-column partial sums/sumsq. Each thread owns 8 contiguous
// channels (bf16x8 loads, 16B/lane). grid: (64 nslice, B, 2{K,V}).
// statsP layout: [(w*BB+b)*64 + ns] x [2][512]
// ---------------------------------------------------------------------------
__global__ __launch_bounds__(256) void stats_partial(
    const u16* __restrict__ Kb, const u16* __restrict__ Vb,
    float* __restrict__ statsP)
{
    const int ns = blockIdx.x;        // 64 slices of 256 rows
    const int b  = blockIdx.y;
    const int w  = blockIdx.z;
    const u16* src = w ? Vb : Kb;

    const int t  = threadIdx.x;
    const int tc = t & 63;            // channel octet: c = tc*8 .. tc*8+7
    const int tn = t >> 6;            // 4-way n interleave
    const int c0 = tc * 8;

    float s[8] = {}, s2[8] = {};
    const int nbase = ns * (NTOT / 64);
    for (int n = nbase + tn; n < nbase + NTOT / 64; n += 4) {
        bf16x8 raw = *(const bf16x8*)(src + (long long)(b * NTOT + n) * HD + c0);
#pragma unroll
        for (int q = 0; q < 8; q++) {
            float x = b2f((u16)raw[q]);
            s[q] += x; s2[q] += x * x;
        }
    }

    __shared__ float red[4][64][16];
#pragma unroll
    for (int q = 0; q < 8; q++) { red[tn][tc][q] = s[q]; red[tn][tc][8 + q] = s2[q]; }
    __syncthreads();
    if (tn == 0) {
        float* p = statsP + ((long long)(w * BB + b) * 64 + ns) * 1024;
#pragma unroll
        for (int q = 0; q < 8; q++) {
            p[c0 + q]       = red[0][tc][q] + red[1][tc][q] + red[2][tc][q] + red[3][tc][q];
            p[512 + c0 + q] = red[0][tc][8+q] + red[1][tc][8+q] + red[2][tc][8+q] + red[3][tc][8+q];
        }
    }
}

// statsF layout [w][b][2][512]: mean then rstd
__global__ __launch_bounds__(512) void stats_final(
    const float* __restrict__ statsP, float* __restrict__ statsF)
{
    const int b = blockIdx.x, w = blockIdx.y;
    const int c = threadIdx.x;
    float s = 0.f, s2 = 0.f;
    const float* base = statsP + ((long long)(w * BB + b) * 64) * 1024;
    for (int ns = 0; ns < 64; ns++) {
        s  += base[ns * 1024 + c];
        s2 += base[ns * 1024 + 512 + c];
    }
    const float m   = s * (1.0f / NTOT);
    const float var = s2 * (1.0f / NTOT) - m * m;
    float* q = statsF + (long long)(w * BB + b) * 1024;
    q[c]       = m;
    q[512 + c] = rsqrtf(var + 1e-5f);
}

// ---------------------------------------------------------------------------
// S[b,h,d,e] += sum_{n in chunk} K[b,n,h*64+d] * V[b,n,h*64+e]  (raw)
// grid: (32 bh, 16 chunks), 256 threads; each thread owns a 4x4 (d,e) block.
// ---------------------------------------------------------------------------
#define NCHUNK 16
__global__ __launch_bounds__(256) void kv_outer(
    const u16* __restrict__ Kb, const u16* __restrict__ Vb,
    float* __restrict__ S)
{
    const int bh = blockIdx.x;
    const int b = bh >> 3, h = bh & 7;
    const int chunk = blockIdx.y;
    const int CH = NTOT / NCHUNK;
    const int n0 = chunk * CH;

    __shared__ float lk[16][64];
    __shared__ float lv[16][64];

    const int t = threadIdx.x;
    const int d0 = (t >> 4) * 4;
    const int e0 = (t & 15) * 4;

    const int lrow = (t & 127) >> 3;  // 0..15
    const int lseg = t & 7;           // 0..7
    const bool isV = t >= 128;
    const u16* src = isV ? Vb : Kb;

    float acc[4][4] = {};

    for (int nn = n0; nn < n0 + CH; nn += 16) {
        bf16x8 raw = *(const bf16x8*)(src + ((long long)(b * NTOT + nn + lrow)) * HD + h * 64 + lseg * 8);
        float* dst = (isV ? &lv[lrow][lseg * 8] : &lk[lrow][lseg * 8]);
#pragma unroll
        for (int q = 0; q < 8; q++) dst[q] = b2f((u16)raw[q]);
        __syncthreads();
#pragma unroll
        for (int n = 0; n < 16; n++) {
            f32x4 kq = *(const f32x4*)&lk[n][d0];
            f32x4 vq = *(const f32x4*)&lv[n][e0];
#pragma unroll
            for (int i = 0; i < 4; i++)
#pragma unroll
                for (int j = 0; j < 4; j++)
                    acc[i][j] += kq[i] * vq[j];
        }
        __syncthreads();
    }

    float* Sp = S + (long long)bh * 4096;
#pragma unroll
    for (int i = 0; i < 4; i++)
#pragma unroll
        for (int j = 0; j < 4; j++)
            atomicAdd(&Sp[(d0 + i) * 64 + (e0 + j)], acc[i][j]);
}

// ---------------------------------------------------------------------------
// kv[d,e] = rk_d*rv_e*(S[d,e]/N - mk_d*mv_e);
// W2T[b,o,h*64+d] = sum_e kv[d,e]*Wo[o,h*64+e]   (Wo read in fp32)
// grid: 32 (bh), 256 threads (one per o).
// ---------------------------------------------------------------------------
__global__ __launch_bounds__(256) void combine(
    const float* __restrict__ S, const float* __restrict__ statsF,
    const float* __restrict__ Wo, u16* __restrict__ W2T)
{
    const int bh = blockIdx.x;
    const int b = bh >> 3, h = bh & 7;
    __shared__ float kv[64][64];
    const int t = threadIdx.x;

    const float* mk = statsF + (long long)(0 * BB + b) * 1024;  // mean; +512 = rstd
    const float* mv = statsF + (long long)(1 * BB + b) * 1024;
    const float* Sp = S + (long long)bh * 4096;

    for (int idx = t; idx < 4096; idx += 256) {
        const int d = idx >> 6, e = idx & 63;
        const int cd = h * 64 + d, ce = h * 64 + e;
        kv[d][e] = (Sp[idx] * (1.0f / NTOT) - mk[cd] * mv[ce]) * mk[512 + cd] * mv[512 + ce];
    }
    __syncthreads();

    const int o = t;  // 0..255
    float wo[64];
    const float* woP = Wo + (long long)o * HD + h * 64;
#pragma unroll
    for (int s4 = 0; s4 < 16; s4++) {
        f32x4 r = *(const f32x4*)(woP + s4 * 4);
        wo[s4 * 4]     = r[0]; wo[s4 * 4 + 1] = r[1];
        wo[s4 * 4 + 2] = r[2]; wo[s4 * 4 + 3] = r[3];
    }
    for (int d = 0; d < 64; d++) {
        float acc = 0.f;
        const f32x4* kvr = (const f32x4*)kv[d];
#pragma unroll
        for (int e4 = 0; e4 < 16; e4++) {
            f32x4 kq = kvr[e4];
            acc += kq[0] * wo[e4 * 4] + kq[1] * wo[e4 * 4 + 1]
                 + kq[2] * wo[e4 * 4 + 2] + kq[3] * wo[e4 * 4 + 3];
        }
        W2T[((long long)b * OUTC + o) * HD + h * 64 + d] = f2b(acc);
    }
}

// ---------------------------------------------------------------------------
extern "C" void kernel_launch(void* const* d_in, const int* in_sizes, int n_in,
                              void* d_out, int out_size, void* d_ws, size_t ws_size,
                              hipStream_t stream)
{
    const float* u_src = (const float*)d_in[0];
    // d_in[1] = pos_src (unused by reference)
    const float* Wq = (const float*)d_in[2];
    const float* Wk = (const float*)d_in[3];
    const float* Wv = (const float*)d_in[4];
    const float* Wo = (const float*)d_in[5];
    const float* bo = (const float*)d_in[6];
    float* out = (float*)d_out;

    char* ws = (char*)d_ws;
    size_t off = 0;
    u16* u_bf  = (u16*)(ws + off); off += 33554432;   // [65536,256] bf16
    u16* Wq_b  = (u16*)(ws + off); off += 262144;     // [512,256] bf16
    u16* Wk_b  = (u16*)(ws + off); off += 262144;
    u16* Wv_b  = (u16*)(ws + off); off += 262144;
    u16* KQ    = (u16*)(ws + off); off += 67108864;   // [65536,512] bf16
    u16* V     = (u16*)(ws + off); off += 67108864;
    float* S   = (float*)(ws + off); off += 524288;   // [32][64][64] f32
    float* stP = (float*)(ws + off); off += 2097152;  // [8][64][2][512] f32
    float* stF = (float*)(ws + off); off += 32768;
    u16* W2T   = (u16*)(ws + off); off += 1048576;    // [4][256][512] bf16

    const dim3 blk(256);
    const int Mtot = BB * NTOT;      // 65536
    const int NU = BB * NTOT * CC;   // 16777216
    const int NW = HD * CC;          // 131072

    // fp32 -> bf16
    cvt_f32_bf16<<<dim3(NU / 2048), blk, 0, stream>>>(u_src, u_bf, NU);
    cvt_f32_bf16<<<dim3(NW / 2048), blk, 0, stream>>>(Wq, Wq_b, NW);
    cvt_f32_bf16<<<dim3(NW / 2048), blk, 0, stream>>>(Wk, Wk_b, NW);
    cvt_f32_bf16<<<dim3(NW / 2048), blk, 0, stream>>>(Wv, Wv_b, NW);

    // K, V projections: [65536,256] x [256,512] -> bf16
    gemm_bt<u16><<<dim3(Mtot / 128, HD / 128, 1), blk, 0, stream>>>(
        u_bf, Wk_b, KQ, nullptr, CC, CC, HD, 0, 0, 0);
    gemm_bt<u16><<<dim3(Mtot / 128, HD / 128, 1), blk, 0, stream>>>(
        u_bf, Wv_b, V, nullptr, CC, CC, HD, 0, 0, 0);

    // instance-norm stats (mean/rstd per (b, channel))
    stats_partial<<<dim3(64, BB, 2), blk, 0, stream>>>(KQ, V, stP);
    stats_final<<<dim3(BB, 2), dim3(512), 0, stream>>>(stP, stF);

    // raw S = K^T V per (b,h)
    hipMemsetAsync(S, 0, 524288, stream);
    kv_outer<<<dim3(BB * HH, NCHUNK), blk, 0, stream>>>(KQ, V, S);

    // kv + fold Wo -> W2T[b, o, c]
    combine<<<dim3(BB * HH), blk, 0, stream>>>(S, stF, Wo, W2T);

    // Q projection (reuse KQ buffer)
    gemm_bt<u16><<<dim3(Mtot / 128, HD / 128, 1), blk, 0, stream>>>(
        u_bf, Wq_b, KQ, nullptr, CC, CC, HD, 0, 0, 0);

    // out[b,n,o] = Q[b,n,:] . W2T[b,o,:] + bo[o]  -> fp32
    gemm_bt<float><<<dim3(NTOT / 128, OUTC / 128, BB), blk, 0, stream>>>(
        KQ, W2T, out, bo, HD, HD, OUTC,
        (long long)NTOT * HD, (long long)OUTC * HD, (long long)NTOT * OUTC);
}

// Round 4
// 274.549 us; speedup vs baseline: 2.4560x; 1.6410x over previous
//
#include <hip/hip_runtime.h>
#include <hip/hip_bf16.h>

// Problem constants (from reference setup_inputs)
#define BB    4
#define NTOT  16384
#define CC    256
#define HH    8
#define DD    64
#define HD    512
#define OUTC  256

typedef unsigned short u16;
typedef __attribute__((ext_vector_type(8))) short bf16x8;   // 8 bf16 in 4 VGPRs
typedef __attribute__((ext_vector_type(4))) float f32x4;

__device__ __forceinline__ float b2f(u16 u) {
    union { float f; unsigned int i; } x; x.i = ((unsigned int)u) << 16; return x.f;
}
__device__ __forceinline__ u16 f2b(float f) {
    union { float f; unsigned int i; } x; x.f = f;
    unsigned int r = x.i + 0x7fffu + ((x.i >> 16) & 1u);   // round-to-nearest-even
    return (u16)(r >> 16);
}

// ---------------------------------------------------------------------------
// prep_u: per 64x64 tile of u[b][n][c] (f32): emit bf16 u_bf (same layout),
// bf16 uT[b][c][n] (transposed), and su[b][c] += column sums (of ROUNDED u).
// grid (NTOT/64, CC/64, BB), 256 threads.
// ---------------------------------------------------------------------------
__global__ __launch_bounds__(256) void prep_u(
    const float* __restrict__ u, u16* __restrict__ u_bf,
    u16* __restrict__ uT, float* __restrict__ su)
{
    const int n0 = blockIdx.x * 64, c0 = blockIdx.y * 64, b = blockIdx.z;
    const int t = threadIdx.x, r = t >> 2, q = t & 3;
    __shared__ float tile[64][65];

    const float* src = u + ((long long)(b * NTOT + n0 + r)) * CC + c0 + q * 16;
    u16 h[16];
#pragma unroll
    for (int it = 0; it < 4; it++) {
        float4 v = *(const float4*)(src + it * 4);
        h[it*4+0] = f2b(v.x); h[it*4+1] = f2b(v.y);
        h[it*4+2] = f2b(v.z); h[it*4+3] = f2b(v.w);
        tile[r][q*16+it*4+0] = b2f(h[it*4+0]);
        tile[r][q*16+it*4+1] = b2f(h[it*4+1]);
        tile[r][q*16+it*4+2] = b2f(h[it*4+2]);
        tile[r][q*16+it*4+3] = b2f(h[it*4+3]);
    }
    {   // u_bf write (row-major, coalesced)
        union { bf16x8 v; u16 s[8]; } p0, p1;
#pragma unroll
        for (int k = 0; k < 8; k++) { p0.s[k] = h[k]; p1.s[k] = h[8+k]; }
        u16* dst = u_bf + ((long long)(b * NTOT + n0 + r)) * CC + c0 + q * 16;
        *(bf16x8*)dst = p0.v;
        *(bf16x8*)(dst + 8) = p1.v;
    }
    __syncthreads();
    {   // uT write: row c = contiguous n
        const int cl = r;                       // c-local row
        union { bf16x8 v; u16 s[8]; } p0, p1;
#pragma unroll
        for (int k = 0; k < 8; k++) {
            p0.s[k] = f2b(tile[q*16+k][cl]);
            p1.s[k] = f2b(tile[q*16+8+k][cl]);
        }
        u16* dst = uT + ((long long)(b * CC + c0 + cl)) * NTOT + n0 + q * 16;
        *(bf16x8*)dst = p0.v;
        *(bf16x8*)(dst + 8) = p1.v;
    }
    if (t < 64) {
        float s = 0.f;
#pragma unroll
        for (int n = 0; n < 64; n++) s += tile[n][t];
        atomicAdd(su + b * CC + c0 + t, s);
    }
}

// ---------------------------------------------------------------------------
// cvt 4 weight matrices (each 131072 f32) to bf16. grid (64, 1, 4).
// ---------------------------------------------------------------------------
__global__ __launch_bounds__(256) void cvt_w4(
    const float* __restrict__ Wq, const float* __restrict__ Wk,
    const float* __restrict__ Wv, const float* __restrict__ Wo,
    u16* __restrict__ q, u16* __restrict__ k,
    u16* __restrict__ v, u16* __restrict__ o)
{
    const int z = blockIdx.z;
    const float* src = z == 0 ? Wq : z == 1 ? Wk : z == 2 ? Wv : Wo;
    u16* dst = z == 0 ? q : z == 1 ? k : z == 2 ? v : o;
    const int i = (blockIdx.x * 256 + threadIdx.x) * 8;
    const float4 a = *(const float4*)(src + i);
    const float4 b = *(const float4*)(src + i + 4);
    union { bf16x8 v; u16 s[8]; } w;
    w.s[0] = f2b(a.x); w.s[1] = f2b(a.y); w.s[2] = f2b(a.z); w.s[3] = f2b(a.w);
    w.s[4] = f2b(b.x); w.s[5] = f2b(b.y); w.s[6] = f2b(b.z); w.s[7] = f2b(b.w);
    *(bf16x8*)(dst + i) = w.v;
}

// ---------------------------------------------------------------------------
// gemm_bt (proven r3): C[m,n] = sum_k A[m,k]*Bm[n,k] (+bias[n]).
// A [M,K] bf16 (row stride lda), Bm [Nm,K] bf16 (row stride K), C (row stride
// ldc) bf16 or f32. 128x128 tile, 4 waves, global_load_lds width=16 staging.
// ---------------------------------------------------------------------------
template <typename CT>
__global__ __launch_bounds__(256) void gemm_bt(
    const u16* __restrict__ A, const u16* __restrict__ Bm,
    CT* __restrict__ C, const float* __restrict__ bias,
    int K, int lda, int ldc,
    long long aStride, long long bStride, long long cStride)
{
    __shared__ u16 As[128 * 32];
    __shared__ u16 Bs[128 * 32];

    const int bz = blockIdx.z;
    A  += (long long)bz * aStride;
    Bm += (long long)bz * bStride;
    C  += (long long)bz * cStride;

    const int m0 = blockIdx.x * 128;
    const int n0 = blockIdx.y * 128;
    const int t  = threadIdx.x;
    const int wv = t >> 6, l = t & 63;
    const int wy = wv >> 1, wx = wv & 1;
    const int r16  = l & 15;
    const int quad = l >> 4;

    const int srow = wv * 16 + (l >> 2);
    const int scol = (l & 3) * 8;

    f32x4 acc[4][4] = {};

    for (int kk = 0; kk < K; kk += 32) {
#pragma unroll
        for (int s = 0; s < 2; s++) {
            const u16* ga = A + (long long)(m0 + s * 64 + srow) * lda + kk + scol;
            __builtin_amdgcn_global_load_lds(
                (const __attribute__((address_space(1))) void*)ga,
                (__attribute__((address_space(3))) void*)(As + s * 2048 + wv * 512),
                16, 0, 0);
            const u16* gb = Bm + (long long)(n0 + s * 64 + srow) * K + kk + scol;
            __builtin_amdgcn_global_load_lds(
                (const __attribute__((address_space(1))) void*)gb,
                (__attribute__((address_space(3))) void*)(Bs + s * 2048 + wv * 512),
                16, 0, 0);
        }
        __syncthreads();

        bf16x8 a[4], b[4];
#pragma unroll
        for (int i = 0; i < 4; i++)
            a[i] = *(const bf16x8*)(As + (wy * 64 + 16 * i + r16) * 32 + quad * 8);
#pragma unroll
        for (int j = 0; j < 4; j++)
            b[j] = *(const bf16x8*)(Bs + (wx * 64 + 16 * j + r16) * 32 + quad * 8);
#pragma unroll
        for (int i = 0; i < 4; i++)
#pragma unroll
            for (int j = 0; j < 4; j++)
                acc[i][j] = __builtin_amdgcn_mfma_f32_16x16x32_bf16(a[i], b[j], acc[i][j], 0, 0, 0);
        __syncthreads();
    }

#pragma unroll
    for (int j = 0; j < 4; j++) {
        const int col = n0 + wx * 64 + 16 * j + r16;
        const float bv = bias ? bias[col] : 0.0f;
#pragma unroll
        for (int i = 0; i < 4; i++) {
#pragma unroll
            for (int r = 0; r < 4; r++) {
                const int row = m0 + wy * 64 + 16 * i + quad * 4 + r;
                const float v = acc[i][j][r] + bv;
                if constexpr (sizeof(CT) == 2) C[(long long)row * ldc + col] = f2b(v);
                else                           C[(long long)row * ldc + col] = v;
            }
        }
    }
}

// ---------------------------------------------------------------------------
// ggemm: Gp[z][i][j] = sum_{n in chunk ck} uT[b][i][n]*uT[b][j][n],
// z = b*32+ck, chunk = 512 n. grid (2, 2, 128). Same structure as gemm_bt.
// ---------------------------------------------------------------------------
__global__ __launch_bounds__(256) void ggemm(
    const u16* __restrict__ uT, float* __restrict__ Gp)
{
    __shared__ u16 As[128 * 32];
    __shared__ u16 Bs[128 * 32];

    const int z = blockIdx.z, b = z >> 5, ck = z & 31;
    const u16* base = uT + (long long)b * CC * NTOT;
    const int m0 = blockIdx.x * 128;
    const int n0 = blockIdx.y * 128;
    const int t  = threadIdx.x;
    const int wv = t >> 6, l = t & 63;
    const int wy = wv >> 1, wx = wv & 1;
    const int r16  = l & 15;
    const int quad = l >> 4;
    const int srow = wv * 16 + (l >> 2);
    const int scol = (l & 3) * 8;

    f32x4 acc[4][4] = {};
    const int k0 = ck * 512;

    for (int kk = k0; kk < k0 + 512; kk += 32) {
#pragma unroll
        for (int s = 0; s < 2; s++) {
            const u16* ga = base + (long long)(m0 + s * 64 + srow) * NTOT + kk + scol;
            __builtin_amdgcn_global_load_lds(
                (const __attribute__((address_space(1))) void*)ga,
                (__attribute__((address_space(3))) void*)(As + s * 2048 + wv * 512),
                16, 0, 0);
            const u16* gb = base + (long long)(n0 + s * 64 + srow) * NTOT + kk + scol;
            __builtin_amdgcn_global_load_lds(
                (const __attribute__((address_space(1))) void*)gb,
                (__attribute__((address_space(3))) void*)(Bs + s * 2048 + wv * 512),
                16, 0, 0);
        }
        __syncthreads();

        bf16x8 a[4], b2[4];
#pragma unroll
        for (int i = 0; i < 4; i++)
            a[i] = *(const bf16x8*)(As + (wy * 64 + 16 * i + r16) * 32 + quad * 8);
#pragma unroll
        for (int j = 0; j < 4; j++)
            b2[j] = *(const bf16x8*)(Bs + (wx * 64 + 16 * j + r16) * 32 + quad * 8);
#pragma unroll
        for (int i = 0; i < 4; i++)
#pragma unroll
            for (int j = 0; j < 4; j++)
                acc[i][j] = __builtin_amdgcn_mfma_f32_16x16x32_bf16(a[i], b2[j], acc[i][j], 0, 0, 0);
        __syncthreads();
    }

    float* Cp = Gp + (long long)z * 65536;
#pragma unroll
    for (int j = 0; j < 4; j++) {
        const int col = n0 + wx * 64 + 16 * j + r16;
#pragma unroll
        for (int i = 0; i < 4; i++)
#pragma unroll
            for (int r = 0; r < 4; r++) {
                const int row = m0 + wy * 64 + 16 * i + quad * 4 + r;
                Cp[row * 256 + col] = acc[i][j][r];
            }
    }
}

// ---------------------------------------------------------------------------
// gred: Gb[b][i][j] = bf16( sum_ck Gp[b*32+ck][i][j] ). grid (256, 4), 256 thr.
// ---------------------------------------------------------------------------
__global__ __launch_bounds__(256) void gred(
    const float* __restrict__ Gp, u16* __restrict__ Gb)
{
    const int i = blockIdx.x, b = blockIdx.y, j = threadIdx.x;
    const float* p = Gp + (long long)(b * 32) * 65536 + i * 256 + j;
    float s = 0.f;
#pragma unroll
    for (int ck = 0; ck < 32; ck++) s += p[(long long)ck * 65536];
    Gb[(long long)b * 65536 + i * 256 + j] = f2b(s);
}

// ---------------------------------------------------------------------------
// stats2: per (b, w, a): mean = (W su)/N, E2 = (P.W)/N, rstd. grid (4,2), 512 thr.
// stF layout [(w*4+b)]: [0..512)=mean, [512..1024)=rstd.
// ---------------------------------------------------------------------------
__global__ __launch_bounds__(512) void stats2(
    const float* __restrict__ P, const u16* __restrict__ Wk_b,
    const u16* __restrict__ Wv_b, const float* __restrict__ su,
    float* __restrict__ stF)
{
    const int b = blockIdx.x, w = blockIdx.y;
    const u16* W = w ? Wv_b : Wk_b;
    __shared__ float suL[256];
    if (threadIdx.x < 256) suL[threadIdx.x] = su[b * CC + threadIdx.x];
    __syncthreads();

    const int a = threadIdx.x;
    const float* Pr = P + ((long long)(w * BB + b) * 512 + a) * 256;
    const u16* Wr = W + a * 256;
    float m = 0.f, e2 = 0.f;
    for (int j8 = 0; j8 < 32; j8++) {
        bf16x8 w8 = *(const bf16x8*)(Wr + j8 * 8);
        f32x4 pa = *(const f32x4*)(Pr + j8 * 8);
        f32x4 pb = *(const f32x4*)(Pr + j8 * 8 + 4);
#pragma unroll
        for (int k = 0; k < 4; k++) {
            float wf = b2f((u16)w8[k]);
            m += wf * suL[j8 * 8 + k]; e2 += wf * pa[k];
        }
#pragma unroll
        for (int k = 0; k < 4; k++) {
            float wf = b2f((u16)w8[4 + k]);
            m += wf * suL[j8 * 8 + 4 + k]; e2 += wf * pb[k];
        }
    }
    m *= (1.0f / NTOT); e2 *= (1.0f / NTOT);
    stF[(long long)(w * BB + b) * 1024 + a] = m;
    stF[(long long)(w * BB + b) * 1024 + 512 + a] = rsqrtf(e2 - m * m + 1e-5f);
}

// ---------------------------------------------------------------------------
// combineS: per (b,h,es): S[d,e]=sum_j Pk[hd,j]*Wv[he,j]; kv=rk rv (S/N - mk mv);
// Zt[c][h*64+e] = sum_d Wq[hd,c] kv[d,e]. grid (32, 4), 256 thr.
// ---------------------------------------------------------------------------
__global__ __launch_bounds__(256) void combineS(
    const float* __restrict__ P, const u16* __restrict__ Wv_b,
    const u16* __restrict__ Wq_b, const float* __restrict__ stF,
    u16* __restrict__ Zt)
{
    const int bh = blockIdx.x, es = blockIdx.y;
    const int b = bh >> 3, h = bh & 7;
    const int e0 = es * 16;
    const int t = threadIdx.x;

    __shared__ float PkL[64][260];   // +4 pad: banks spread, 16B aligned
    __shared__ float WvL[16][260];
    __shared__ u16  WqTL[256][72];   // transposed Wq_h, row = c
    __shared__ float kvL[64][20];

    // stage Pk rows (h*64 .. +64)
    const float* Pk = P + ((long long)b * 512 + h * 64) * 256;
    for (int it = 0; it < 16; it++) {
        int idx = it * 1024 + t * 4;
        int rr = idx >> 8, cc = idx & 255;
        *(f32x4*)&PkL[rr][cc] = *(const f32x4*)(Pk + rr * 256 + cc);
    }
    // stage Wv rows (h*64+e0 .. +16) as f32
    const u16* Wv = Wv_b + (h * 64 + e0) * 256;
    for (int it = 0; it < 2; it++) {
        int idx = it * 2048 + t * 8;
        int rr = idx >> 8, cc = idx & 255;
        bf16x8 raw = *(const bf16x8*)(Wv + rr * 256 + cc);
        f32x4 lo, hi;
#pragma unroll
        for (int k = 0; k < 4; k++) { lo[k] = b2f((u16)raw[k]); hi[k] = b2f((u16)raw[4 + k]); }
        *(f32x4*)&WvL[rr][cc] = lo;
        *(f32x4*)&WvL[rr][cc + 4] = hi;
    }
    // stage Wq_h transposed: WqTL[c][d] = Wq[h*64+d][c]
    {
        const int d = t >> 2, q = t & 3;
        const u16* Wq = Wq_b + (h * 64 + d) * 256 + q * 64;
#pragma unroll
        for (int k8 = 0; k8 < 8; k8++) {
            bf16x8 raw = *(const bf16x8*)(Wq + k8 * 8);
#pragma unroll
            for (int k = 0; k < 8; k++)
                WqTL[q * 64 + k8 * 8 + k][d] = (u16)raw[k];
        }
    }
    __syncthreads();

    // phase 1: S and kv
    {
        const int d = t >> 2;
        const int eb = (t & 3) * 4;
        float acc4[4] = {};
        for (int j4 = 0; j4 < 64; j4++) {
            f32x4 pk = *(const f32x4*)&PkL[d][j4 * 4];
#pragma unroll
            for (int ee = 0; ee < 4; ee++) {
                f32x4 wv = *(const f32x4*)&WvL[eb + ee][j4 * 4];
                acc4[ee] += pk[0] * wv[0] + pk[1] * wv[1] + pk[2] * wv[2] + pk[3] * wv[3];
            }
        }
        const float mk = stF[(long long)b * 1024 + h * 64 + d];
        const float rk = stF[(long long)b * 1024 + 512 + h * 64 + d];
#pragma unroll
        for (int ee = 0; ee < 4; ee++) {
            const int e = e0 + eb + ee;
            const float mv = stF[(long long)(BB + b) * 1024 + h * 64 + e];
            const float rv = stF[(long long)(BB + b) * 1024 + 512 + h * 64 + e];
            kvL[d][eb + ee] = rk * rv * (acc4[ee] * (1.0f / NTOT) - mk * mv);
        }
    }
    __syncthreads();

    // phase 2: Zt[c][h*64+e0..+16] = sum_d Wq[hd,c]*kv[d,e]
    {
        const int c = t;
        float wq[64];
#pragma unroll
        for (int k8 = 0; k8 < 8; k8++) {
            bf16x8 raw = *(const bf16x8*)&WqTL[c][k8 * 8];
#pragma unroll
            for (int k = 0; k < 8; k++) wq[k8 * 8 + k] = b2f((u16)raw[k]);
        }
        float acc[16] = {};
        for (int d = 0; d < 64; d++) {
#pragma unroll
            for (int e4 = 0; e4 < 4; e4++) {
                f32x4 kv = *(const f32x4*)&kvL[d][e4 * 4];
#pragma unroll
                for (int i = 0; i < 4; i++) acc[e4 * 4 + i] += wq[d] * kv[i];
            }
        }
        union { bf16x8 v; u16 s[8]; } p0, p1;
#pragma unroll
        for (int k = 0; k < 8; k++) { p0.s[k] = f2b(acc[k]); p1.s[k] = f2b(acc[8 + k]); }
        u16* dst = Zt + ((long long)(b * CC + c)) * HD + h * 64 + e0;
        *(bf16x8*)dst = p0.v;
        *(bf16x8*)(dst + 8) = p1.v;
    }
}

// ---------------------------------------------------------------------------
extern "C" void kernel_launch(void* const* d_in, const int* in_sizes, int n_in,
                              void* d_out, int out_size, void* d_ws, size_t ws_size,
                              hipStream_t stream)
{
    const float* u_src = (const float*)d_in[0];
    // d_in[1] = pos_src (unused)
    const float* Wq = (const float*)d_in[2];
    const float* Wk = (const float*)d_in[3];
    const float* Wv = (const float*)d_in[4];
    const float* Wo = (const float*)d_in[5];
    const float* bo = (const float*)d_in[6];
    float* out = (float*)d_out;

    char* ws = (char*)d_ws;
    size_t off = 0;
    u16*  u_bf = (u16*)(ws + off);  off += 33554432;   // [4][16384][256] bf16
    u16*  uT   = (u16*)(ws + off);  off += 33554432;   // [4][256][16384] bf16
    float* Gp  = (float*)(ws + off); off += 33554432;  // [128][256][256] f32
    float* P   = (float*)(ws + off); off += 4194304;   // [2][4][512][256] f32
    u16*  Gb   = (u16*)(ws + off);  off += 524288;     // [4][256][256] bf16
    u16*  Wq_b = (u16*)(ws + off);  off += 262144;
    u16*  Wk_b = (u16*)(ws + off);  off += 262144;
    u16*  Wv_b = (u16*)(ws + off);  off += 262144;
    u16*  Wo_b = (u16*)(ws + off);  off += 262144;     // [256][512] bf16
    float* su  = (float*)(ws + off); off += 4096;      // [4][256] f32
    float* stF = (float*)(ws + off); off += 32768;     // [2][4][2][512] f32
    u16*  Zt   = (u16*)(ws + off);  off += 1048576;    // [4][256][512] bf16
    u16*  Ft   = (u16*)(ws + off);  off += 524288;     // [4][256][256] bf16

    const dim3 blk(256);

    hipMemsetAsync(su, 0, 4096, stream);

    // u -> u_bf, uT, su
    prep_u<<<dim3(NTOT / 64, CC / 64, BB), blk, 0, stream>>>(u_src, u_bf, uT, su);

    // weights -> bf16
    cvt_w4<<<dim3(64, 1, 4), blk, 0, stream>>>(Wq, Wk, Wv, Wo, Wq_b, Wk_b, Wv_b, Wo_b);

    // G = uT uT^T (split-K 32) then reduce -> bf16
    ggemm<<<dim3(2, 2, 128), blk, 0, stream>>>(uT, Gp);
    gred<<<dim3(256, BB), blk, 0, stream>>>(Gp, Gb);

    // P[w][b] = W G_b : [512x256]x[256x256]
    gemm_bt<float><<<dim3(4, 2, BB), blk, 0, stream>>>(
        Wk_b, Gb, P, nullptr, 256, 256, 256, 0, 65536, 131072);
    gemm_bt<float><<<dim3(4, 2, BB), blk, 0, stream>>>(
        Wv_b, Gb, P + (long long)BB * 131072, nullptr, 256, 256, 256, 0, 65536, 131072);

    // mean / rstd
    stats2<<<dim3(BB, 2), dim3(512), 0, stream>>>(P, Wk_b, Wv_b, su, stF);

    // S -> kv -> Zt
    combineS<<<dim3(BB * HH, 4), blk, 0, stream>>>(P, Wv_b, Wq_b, stF, Zt);

    // Ft[b] = Wo Zt_b^T : [256x512]x[512x256]
    gemm_bt<u16><<<dim3(2, 2, BB), blk, 0, stream>>>(
        Wo_b, Zt, Ft, nullptr, 512, 512, 256, 0, 131072, 65536);

    // out = u_bf Ft^T + bo : [16384x256]x[256x256] per b
    gemm_bt<float><<<dim3(128, 2, BB), blk, 0, stream>>>(
        u_bf, Ft, out, bo, 256, 256, 256,
        (long long)NTOT * CC, 65536, (long long)NTOT * OUTC);
}

// Round 5
// 254.217 us; speedup vs baseline: 2.6525x; 1.0800x over previous
//
#include <hip/hip_runtime.h>
#include <hip/hip_bf16.h>

// Problem constants (from reference setup_inputs)
#define BB    4
#define NTOT  16384
#define CC    256
#define HH    8
#define DD    64
#define HD    512
#define OUTC  256

typedef unsigned short u16;
typedef __attribute__((ext_vector_type(8))) short bf16x8;   // 8 bf16 in 4 VGPRs
typedef __attribute__((ext_vector_type(4))) float f32x4;
typedef __attribute__((ext_vector_type(4))) short u16x4;

__device__ __forceinline__ float b2f(u16 u) {
    union { float f; unsigned int i; } x; x.i = ((unsigned int)u) << 16; return x.f;
}
__device__ __forceinline__ u16 f2b(float f) {
    union { float f; unsigned int i; } x; x.f = f;
    unsigned int r = x.i + 0x7fffu + ((x.i >> 16) & 1u);   // round-to-nearest-even
    return (u16)(r >> 16);
}

#define GLD(gp, lp) __builtin_amdgcn_global_load_lds( \
    (const __attribute__((address_space(1))) void*)(gp), \
    (__attribute__((address_space(3))) void*)(lp), 16, 0, 0)

#define MFMA(a, b, c) __builtin_amdgcn_mfma_f32_16x16x32_bf16((a), (b), (c), 0, 0, 0)

// ---------------------------------------------------------------------------
// prep_u: 64x64 tile of u[b][n][c] f32 -> u_bf (bf16, same layout) and
// uT[b][c][n] (bf16, transposed). u16 LDS tile, pad 74 (2-way-free banks).
// grid (256, 4, 4), 256 threads.
// ---------------------------------------------------------------------------
__global__ __launch_bounds__(256) void prep_u(
    const float* __restrict__ u, u16* __restrict__ u_bf, u16* __restrict__ uT)
{
    const int n0 = blockIdx.x * 64, c0 = blockIdx.y * 64, b = blockIdx.z;
    const int t = threadIdx.x, r = t >> 2, q = t & 3;
    __shared__ u16 tile[64][74];

    const float* src = u + ((long long)(b * NTOT + n0 + r)) * CC + c0 + q * 16;
    u16 h[16];
#pragma unroll
    for (int it = 0; it < 4; it++) {
        float4 v = *(const float4*)(src + it * 4);
        h[it*4+0] = f2b(v.x); h[it*4+1] = f2b(v.y);
        h[it*4+2] = f2b(v.z); h[it*4+3] = f2b(v.w);
    }
    {   // u_bf (coalesced)
        union { bf16x8 v; u16 s[8]; } p0, p1;
#pragma unroll
        for (int k = 0; k < 8; k++) { p0.s[k] = h[k]; p1.s[k] = h[8+k]; }
        u16* dst = u_bf + ((long long)(b * NTOT + n0 + r)) * CC + c0 + q * 16;
        *(bf16x8*)dst = p0.v;
        *(bf16x8*)(dst + 8) = p1.v;
    }
    {   // LDS tile write as packed u32
        unsigned int* trow = (unsigned int*)&tile[r][q * 16];
#pragma unroll
        for (int k2 = 0; k2 < 8; k2++)
            trow[k2] = (unsigned int)h[2*k2] | ((unsigned int)h[2*k2+1] << 16);
    }
    __syncthreads();
    {   // transposed read: thread owns column c = t>>2, rows q*16..+16
        const int c = r;
        union { bf16x8 v; u16 s[8]; } o0, o1;
#pragma unroll
        for (int k = 0; k < 8; k++) {
            o0.s[k] = tile[q * 16 + k][c];
            o1.s[k] = tile[q * 16 + 8 + k][c];
        }
        u16* dT = uT + ((long long)(b * CC + c0 + c)) * NTOT + n0 + q * 16;
        *(bf16x8*)dT = o0.v;
        *(bf16x8*)(dT + 8) = o1.v;
    }
}

// ---------------------------------------------------------------------------
// cvt 4 weight matrices (each 131072 f32) to bf16. grid (64, 1, 4).
// ---------------------------------------------------------------------------
__global__ __launch_bounds__(256) void cvt_w4(
    const float* __restrict__ Wq, const float* __restrict__ Wk,
    const float* __restrict__ Wv, const float* __restrict__ Wo,
    u16* __restrict__ q, u16* __restrict__ k,
    u16* __restrict__ v, u16* __restrict__ o)
{
    const int z = blockIdx.z;
    const float* src = z == 0 ? Wq : z == 1 ? Wk : z == 2 ? Wv : Wo;
    u16* dst = z == 0 ? q : z == 1 ? k : z == 2 ? v : o;
    const int i = (blockIdx.x * 256 + threadIdx.x) * 8;
    const float4 a = *(const float4*)(src + i);
    const float4 b = *(const float4*)(src + i + 4);
    union { bf16x8 v; u16 s[8]; } w;
    w.s[0] = f2b(a.x); w.s[1] = f2b(a.y); w.s[2] = f2b(a.z); w.s[3] = f2b(a.w);
    w.s[4] = f2b(b.x); w.s[5] = f2b(b.y); w.s[6] = f2b(b.z); w.s[7] = f2b(b.w);
    *(bf16x8*)(dst + i) = w.v;
}

// ---------------------------------------------------------------------------
// ggemm v2: Gp[z][i][j] = sum_{n in chunk ck} uT[b][i][n]*uT[b][j][n],
// z = b*32+ck (K-chunk 512). Single shared 256x32 LDS tile (A==B), 512 thr,
// 8 waves in 4x2, full 256x256 output per block. Also emits per-chunk column
// sums suP[z][c] (row sums of uT = su partials). grid (128).
// ---------------------------------------------------------------------------
__global__ __launch_bounds__(512) void ggemm(
    const u16* __restrict__ uT, float* __restrict__ Gp, float* __restrict__ suP)
{
    __shared__ u16 Ts[256 * 32];   // 16 KB
    const int z = blockIdx.x, b = z >> 5, ck = z & 31;
    const u16* base = uT + (long long)b * CC * NTOT + ck * 512;
    const int t = threadIdx.x, w = t >> 6, l = t & 63;
    const int wy = w >> 1, wx = w & 1;      // 4 m-groups x 2 n-groups
    const int r16 = l & 15, quad = l >> 4;
    const int srow = w * 16 + (l >> 2), scol = (l & 3) * 8;

    f32x4 acc[4][8] = {};
    float su = 0.f;

    for (int kk = 0; kk < 512; kk += 32) {
#pragma unroll
        for (int s = 0; s < 2; s++)
            GLD(base + (long long)(s * 128 + srow) * NTOT + kk + scol,
                Ts + s * 4096 + w * 512);
        __syncthreads();

        if (t < 256) {   // su partial: row t of this chunk-tile
            const u16* rw = Ts + t * 32;
            float s1 = 0.f;
#pragma unroll
            for (int k8 = 0; k8 < 4; k8++) {
                bf16x8 rv = *(const bf16x8*)(rw + k8 * 8);
#pragma unroll
                for (int k = 0; k < 8; k++) s1 += b2f((u16)rv[k]);
            }
            su += s1;
        }
        bf16x8 a[4], bb[8];
#pragma unroll
        for (int i = 0; i < 4; i++)
            a[i] = *(const bf16x8*)(Ts + (wy * 64 + 16 * i + r16) * 32 + quad * 8);
#pragma unroll
        for (int j = 0; j < 8; j++)
            bb[j] = *(const bf16x8*)(Ts + (wx * 128 + 16 * j + r16) * 32 + quad * 8);
#pragma unroll
        for (int i = 0; i < 4; i++)
#pragma unroll
            for (int j = 0; j < 8; j++)
                acc[i][j] = MFMA(a[i], bb[j], acc[i][j]);
        __syncthreads();
    }

    float* Cp = Gp + (long long)z * 65536;
#pragma unroll
    for (int i = 0; i < 4; i++)
#pragma unroll
        for (int j = 0; j < 8; j++)
#pragma unroll
            for (int rr = 0; rr < 4; rr++)
                Cp[(wy * 64 + 16 * i + quad * 4 + rr) * 256 + wx * 128 + 16 * j + r16]
                    = acc[i][j][rr];
    if (t < 256) suP[z * 256 + t] = su;
}

// ---------------------------------------------------------------------------
// gred: Gb[b][i][j] = bf16(sum_ck Gp); block i==0 also reduces suP -> su.
// grid (256, 4), 256 thr.
// ---------------------------------------------------------------------------
__global__ __launch_bounds__(256) void gred(
    const float* __restrict__ Gp, const float* __restrict__ suP,
    u16* __restrict__ Gb, float* __restrict__ su)
{
    const int i = blockIdx.x, b = blockIdx.y, j = threadIdx.x;
    const float* p = Gp + (long long)(b * 32) * 65536 + i * 256 + j;
    float s = 0.f;
#pragma unroll
    for (int ck = 0; ck < 32; ck++) s += p[(long long)ck * 65536];
    Gb[(long long)b * 65536 + i * 256 + j] = f2b(s);
    if (i == 0) {
        float s2 = 0.f;
#pragma unroll
        for (int ck = 0; ck < 32; ck++) s2 += suP[(b * 32 + ck) * 256 + j];
        su[b * 256 + j] = s2;
    }
}

// ---------------------------------------------------------------------------
// midend: per (b,h) block (grid 32, 256 thr): Pk=Wk_h*G, Pv=Wv_h*G (MFMA,
// frags from L2-hot global), stats (mean via su, E2 via P.W), S=Pk*Wv^T,
// kv = rk rv (S/N - mk mv), Zt[c][h*64+e] = sum_d Wq[hd,c] kv[d,e].
// LDS pool 40KB: [0,32K)=PkL (chunk-tiles) then [0,8K)=kvTL + [8K,40K)=WqTL.
// ---------------------------------------------------------------------------
__global__ __launch_bounds__(256) void midend(
    const u16* __restrict__ Gb, const float* __restrict__ su,
    const u16* __restrict__ Wk_b, const u16* __restrict__ Wv_b,
    const u16* __restrict__ Wq_b, u16* __restrict__ Zt)
{
    __shared__ u16 pool[20480];   // 40 KB
    __shared__ float e2kL[64], e2vL[64], mkL[64], rkL[64], mvL[64], rvL[64];

    const int bx = blockIdx.x, b = bx >> 3, h = bx & 7;
    const int t = threadIdx.x, w = t >> 6, l = t & 63;
    const int r16 = l & 15, quad = l >> 4;

    const u16* WkH = Wk_b + (h * 64) * 256;
    const u16* WvH = Wv_b + (h * 64) * 256;
    const u16* GbB = Gb + (long long)b * 65536;

    if (t < 64) e2kL[t] = 0.f;
    else if (t < 128) e2vL[t - 64] = 0.f;

    // ---- P-phase: Pk/Pv [64x256], wave w owns cols w*64..+64 ----
    f32x4 acck[4][4] = {}, accv[4][4] = {};
    for (int ch = 0; ch < 8; ch++) {
        const int kk = ch * 32 + quad * 8;
        bf16x8 ak[4], av[4], bg[4];
#pragma unroll
        for (int i = 0; i < 4; i++) {
            ak[i] = *(const bf16x8*)(WkH + (16 * i + r16) * 256 + kk);
            av[i] = *(const bf16x8*)(WvH + (16 * i + r16) * 256 + kk);
        }
#pragma unroll
        for (int j = 0; j < 4; j++)
            bg[j] = *(const bf16x8*)(GbB + (w * 64 + 16 * j + r16) * 256 + kk);
#pragma unroll
        for (int i = 0; i < 4; i++)
#pragma unroll
            for (int j = 0; j < 4; j++) {
                acck[i][j] = MFMA(ak[i], bg[j], acck[i][j]);
                accv[i][j] = MFMA(av[i], bg[j], accv[i][j]);
            }
    }
    __syncthreads();   // e2 zero-init visible; pool region free

    // ---- write PkL (chunk-tiles over j) + e2 partials ----
    u16* PkL = pool;
#pragma unroll
    for (int i = 0; i < 4; i++) {
#pragma unroll
        for (int rr = 0; rr < 4; rr++) {
            const int a = 16 * i + quad * 4 + rr;
            float e2k = 0.f, e2v = 0.f;
#pragma unroll
            for (int jt = 0; jt < 4; jt++) {
                const int j = w * 64 + 16 * jt + r16;
                PkL[(j >> 5) * 2048 + a * 32 + (j & 31)] = f2b(acck[i][jt][rr]);
                e2k += acck[i][jt][rr] * b2f(WkH[a * 256 + j]);
                e2v += accv[i][jt][rr] * b2f(WvH[a * 256 + j]);
            }
            atomicAdd(&e2kL[a], e2k);
            atomicAdd(&e2vL[a], e2v);
        }
    }
    __syncthreads();

    // ---- stats: t<64 -> K channel a=t; 64<=t<128 -> V channel ----
    if (t < 128) {
        const int a = t & 63;
        const u16* Wrow = (t < 64) ? (WkH + a * 256) : (WvH + a * 256);
        const float* suB = su + b * 256;
        float m = 0.f;
        for (int c8 = 0; c8 < 32; c8++) {
            bf16x8 wr = *(const bf16x8*)(Wrow + c8 * 8);
#pragma unroll
            for (int k = 0; k < 8; k++) m += b2f((u16)wr[k]) * suB[c8 * 8 + k];
        }
        m *= (1.0f / NTOT);
        const float e2 = ((t < 64) ? e2kL[a] : e2vL[a]) * (1.0f / NTOT);
        const float r = rsqrtf(e2 - m * m + 1e-5f);
        if (t < 64) { mkL[a] = m; rkL[a] = r; }
        else        { mvL[a] = m; rvL[a] = r; }
    }
    __syncthreads();

    // ---- S-phase: S[d,e] = sum_j Pk[d,j]*Wv[e,j]; wave -> 32x32 quadrant ----
    const int mh = (w >> 1) * 32, nh = (w & 1) * 32;
    float mkR[2][4], rkR[2][4], mvR[2], rvR[2];
#pragma unroll
    for (int i = 0; i < 2; i++)
#pragma unroll
        for (int rr = 0; rr < 4; rr++) {
            mkR[i][rr] = mkL[mh + 16 * i + quad * 4 + rr];
            rkR[i][rr] = rkL[mh + 16 * i + quad * 4 + rr];
        }
#pragma unroll
    for (int j = 0; j < 2; j++) {
        mvR[j] = mvL[nh + 16 * j + r16];
        rvR[j] = rvL[nh + 16 * j + r16];
    }

    f32x4 accs[2][2] = {};
    for (int ch = 0; ch < 8; ch++) {
        const int ko = quad * 8;
        bf16x8 ap[2], bv[2];
#pragma unroll
        for (int i = 0; i < 2; i++)
            ap[i] = *(const bf16x8*)(PkL + ch * 2048 + (mh + 16 * i + r16) * 32 + ko);
#pragma unroll
        for (int j = 0; j < 2; j++)
            bv[j] = *(const bf16x8*)(WvH + (nh + 16 * j + r16) * 256 + ch * 32 + ko);
#pragma unroll
        for (int i = 0; i < 2; i++)
#pragma unroll
            for (int j = 0; j < 2; j++)
                accs[i][j] = MFMA(ap[i], bv[j], accs[i][j]);
    }
    __syncthreads();   // all PkL reads done before overlay

    // ---- kv -> kvTL; stage WqTL (transposed Wq_h) ----
    u16* kvTL = pool;            // 8 KB: [2][64][32]
    u16* WqTL = pool + 4096;     // 32 KB: [2][256][32]
#pragma unroll
    for (int i = 0; i < 2; i++)
#pragma unroll
        for (int j = 0; j < 2; j++)
#pragma unroll
            for (int rr = 0; rr < 4; rr++) {
                const int d = mh + 16 * i + quad * 4 + rr;
                const int e = nh + 16 * j + r16;
                const float kv = rkR[i][rr] * rvR[j] *
                    (accs[i][j][rr] * (1.0f / NTOT) - mkR[i][rr] * mvR[j]);
                kvTL[(d >> 5) * 2048 + e * 32 + (d & 31)] = f2b(kv);
            }
    {
        const int d = t >> 2, q = t & 3;
        const u16* Wrow = Wq_b + (h * 64 + d) * 256 + q * 64;
#pragma unroll
        for (int s = 0; s < 8; s++) {
            bf16x8 raw = *(const bf16x8*)(Wrow + s * 8);
#pragma unroll
            for (int k = 0; k < 8; k++) {
                const int c = q * 64 + s * 8 + k;
                WqTL[(d >> 5) * 8192 + c * 32 + (d & 31)] = (u16)raw[k];
            }
        }
    }
    __syncthreads();

    // ---- Y-phase: Y[e,c] = sum_d kvT[e,d]*WqT[c,d]; wave w -> cols w*64 ----
    f32x4 accy[4][4] = {};
#pragma unroll
    for (int ch = 0; ch < 2; ch++) {
        const int ko = quad * 8;
        bf16x8 akv[4], bq[4];
#pragma unroll
        for (int i = 0; i < 4; i++)
            akv[i] = *(const bf16x8*)(kvTL + ch * 2048 + (16 * i + r16) * 32 + ko);
#pragma unroll
        for (int j = 0; j < 4; j++)
            bq[j] = *(const bf16x8*)(WqTL + ch * 8192 + (w * 64 + 16 * j + r16) * 32 + ko);
#pragma unroll
        for (int i = 0; i < 4; i++)
#pragma unroll
            for (int j = 0; j < 4; j++)
                accy[i][j] = MFMA(akv[i], bq[j], accy[i][j]);
    }
#pragma unroll
    for (int i = 0; i < 4; i++)
#pragma unroll
        for (int j = 0; j < 4; j++) {
            const int c = w * 64 + 16 * j + r16;
            const int e0 = 16 * i + quad * 4;
            union { u16x4 v; u16 s[4]; } pk;
#pragma unroll
            for (int rr = 0; rr < 4; rr++) pk.s[rr] = f2b(accy[i][j][rr]);
            *(u16x4*)(Zt + ((long long)(b * 256 + c)) * 512 + h * 64 + e0) = pk.v;
        }
}

// ---------------------------------------------------------------------------
// gemm_bt (proven r3/r4): C[m,n] = sum_k A[m,k]*Bm[n,k] (+bias[n]).
// ---------------------------------------------------------------------------
template <typename CT>
__global__ __launch_bounds__(256) void gemm_bt(
    const u16* __restrict__ A, const u16* __restrict__ Bm,
    CT* __restrict__ C, const float* __restrict__ bias,
    int K, int lda, int ldc,
    long long aStride, long long bStride, long long cStride)
{
    __shared__ u16 As[128 * 32];
    __shared__ u16 Bs[128 * 32];

    const int bz = blockIdx.z;
    A  += (long long)bz * aStride;
    Bm += (long long)bz * bStride;
    C  += (long long)bz * cStride;

    const int m0 = blockIdx.x * 128;
    const int n0 = blockIdx.y * 128;
    const int t  = threadIdx.x;
    const int wv = t >> 6, l = t & 63;
    const int wy = wv >> 1, wx = wv & 1;
    const int r16  = l & 15;
    const int quad = l >> 4;
    const int srow = wv * 16 + (l >> 2);
    const int scol = (l & 3) * 8;

    f32x4 acc[4][4] = {};

    for (int kk = 0; kk < K; kk += 32) {
#pragma unroll
        for (int s = 0; s < 2; s++) {
            GLD(A + (long long)(m0 + s * 64 + srow) * lda + kk + scol,
                As + s * 2048 + wv * 512);
            GLD(Bm + (long long)(n0 + s * 64 + srow) * K + kk + scol,
                Bs + s * 2048 + wv * 512);
        }
        __syncthreads();

        bf16x8 a[4], b[4];
#pragma unroll
        for (int i = 0; i < 4; i++)
            a[i] = *(const bf16x8*)(As + (wy * 64 + 16 * i + r16) * 32 + quad * 8);
#pragma unroll
        for (int j = 0; j < 4; j++)
            b[j] = *(const bf16x8*)(Bs + (wx * 64 + 16 * j + r16) * 32 + quad * 8);
#pragma unroll
        for (int i = 0; i < 4; i++)
#pragma unroll
            for (int j = 0; j < 4; j++)
                acc[i][j] = MFMA(a[i], b[j], acc[i][j]);
        __syncthreads();
    }

#pragma unroll
    for (int j = 0; j < 4; j++) {
        const int col = n0 + wx * 64 + 16 * j + r16;
        const float bv = bias ? bias[col] : 0.0f;
#pragma unroll
        for (int i = 0; i < 4; i++) {
#pragma unroll
            for (int r = 0; r < 4; r++) {
                const int row = m0 + wy * 64 + 16 * i + quad * 4 + r;
                const float v = acc[i][j][r] + bv;
                if constexpr (sizeof(CT) == 2) C[(long long)row * ldc + col] = f2b(v);
                else                           C[(long long)row * ldc + col] = v;
            }
        }
    }
}

// ---------------------------------------------------------------------------
extern "C" void kernel_launch(void* const* d_in, const int* in_sizes, int n_in,
                              void* d_out, int out_size, void* d_ws, size_t ws_size,
                              hipStream_t stream)
{
    const float* u_src = (const float*)d_in[0];
    // d_in[1] = pos_src (unused)
    const float* Wq = (const float*)d_in[2];
    const float* Wk = (const float*)d_in[3];
    const float* Wv = (const float*)d_in[4];
    const float* Wo = (const float*)d_in[5];
    const float* bo = (const float*)d_in[6];
    float* out = (float*)d_out;

    char* ws = (char*)d_ws;
    size_t off = 0;
    u16*  u_bf = (u16*)(ws + off);  off += 33554432;   // [4][16384][256] bf16
    u16*  uT   = (u16*)(ws + off);  off += 33554432;   // [4][256][16384] bf16
    float* Gp  = (float*)(ws + off); off += 33554432;  // [128][256][256] f32
    float* suP = (float*)(ws + off); off += 131072;    // [128][256] f32
    u16*  Gb   = (u16*)(ws + off);  off += 524288;     // [4][256][256] bf16
    u16*  Wq_b = (u16*)(ws + off);  off += 262144;
    u16*  Wk_b = (u16*)(ws + off);  off += 262144;
    u16*  Wv_b = (u16*)(ws + off);  off += 262144;
    u16*  Wo_b = (u16*)(ws + off);  off += 262144;     // [256][512] bf16
    float* su  = (float*)(ws + off); off += 4096;      // [4][256] f32
    u16*  Zt   = (u16*)(ws + off);  off += 1048576;    // [4][256][512] bf16
    u16*  Ft   = (u16*)(ws + off);  off += 524288;     // [4][256][256] bf16

    const dim3 blk(256);

    // u -> u_bf + uT
    prep_u<<<dim3(NTOT / 64, CC / 64, BB), blk, 0, stream>>>(u_src, u_bf, uT);

    // weights -> bf16
    cvt_w4<<<dim3(64, 1, 4), blk, 0, stream>>>(Wq, Wk, Wv, Wo, Wq_b, Wk_b, Wv_b, Wo_b);

    // G = uT uT^T (split-K 32, shared operand) + su partials
    ggemm<<<dim3(BB * 32), dim3(512), 0, stream>>>(uT, Gp, suP);
    gred<<<dim3(256, BB), blk, 0, stream>>>(Gp, suP, Gb, su);

    // P/stats/S/kv/Zt fused
    midend<<<dim3(BB * HH), blk, 0, stream>>>(Gb, su, Wk_b, Wv_b, Wq_b, Zt);

    // Ft[b] = Wo Zt_b^T : [256x512]x[512x256]
    gemm_bt<u16><<<dim3(2, 2, BB), blk, 0, stream>>>(
        Wo_b, Zt, Ft, nullptr, 512, 512, 256, 0, 131072, 65536);

    // out = u_bf Ft^T + bo : [16384x256]x[256x256] per b
    gemm_bt<float><<<dim3(128, 2, BB), blk, 0, stream>>>(
        u_bf, Ft, out, bo, 256, 256, 256,
        (long long)NTOT * CC, 65536, (long long)NTOT * OUTC);
}

// Round 6
// 253.295 us; speedup vs baseline: 2.6621x; 1.0036x over previous
//
#include <hip/hip_runtime.h>
#include <hip/hip_bf16.h>

// Problem constants (from reference setup_inputs)
#define BB    4
#define NTOT  16384
#define CC    256
#define HH    8
#define DD    64
#define HD    512
#define OUTC  256

typedef unsigned short u16;
typedef unsigned int u32;
typedef __attribute__((ext_vector_type(8))) short bf16x8;   // 8 bf16 in 4 VGPRs
typedef __attribute__((ext_vector_type(4))) float f32x4;
typedef __attribute__((ext_vector_type(4))) short u16x4;
typedef __attribute__((ext_vector_type(4))) u32 u32x4;

__device__ __forceinline__ float b2f(u16 u) {
    union { float f; u32 i; } x; x.i = ((u32)u) << 16; return x.f;
}
__device__ __forceinline__ u16 f2b(float f) {
    union { float f; u32 i; } x; x.f = f;
    u32 r = x.i + 0x7fffu + ((x.i >> 16) & 1u);   // round-to-nearest-even
    return (u16)(r >> 16);
}

#define GLD(gp, lp) __builtin_amdgcn_global_load_lds( \
    (const __attribute__((address_space(1))) void*)(gp), \
    (__attribute__((address_space(3))) void*)(lp), 16, 0, 0)

#define MFMA(a, b, c) __builtin_amdgcn_mfma_f32_16x16x32_bf16((a), (b), (c), 0, 0, 0)

// ---------------------------------------------------------------------------
// prep_u v3: 64x64 tile of u[b][n][c] f32 -> u_bf (bf16) and uT[b][c][n].
// Pair-packed u32 LDS transpose ([32 row-pairs][72 cols], octet-XOR swizzle):
// write 2x b128, read 8x b32 (2-way-free banks), store uint4 with no repack.
// grid (256, 5, 4): y==4 plane converts the 4 weight matrices to bf16.
// ---------------------------------------------------------------------------
__global__ __launch_bounds__(256) void prep_u(
    const float* __restrict__ u, u16* __restrict__ u_bf, u16* __restrict__ uT,
    const float* __restrict__ Wq, const float* __restrict__ Wk,
    const float* __restrict__ Wv, const float* __restrict__ Wo,
    u16* __restrict__ Wq_b, u16* __restrict__ Wk_b,
    u16* __restrict__ Wv_b, u16* __restrict__ Wo_b)
{
    __shared__ u32 LA[32][72];
    const int t = threadIdx.x;

    if (blockIdx.y == 4) {           // fused weight conversion
        if (blockIdx.x >= 64) return;
        const int z = blockIdx.z;
        const float* src = z == 0 ? Wq : z == 1 ? Wk : z == 2 ? Wv : Wo;
        u16* dst = z == 0 ? Wq_b : z == 1 ? Wk_b : z == 2 ? Wv_b : Wo_b;
        const int i = (blockIdx.x * 256 + t) * 8;
        const float4 a = *(const float4*)(src + i);
        const float4 b = *(const float4*)(src + i + 4);
        union { bf16x8 v; u16 s[8]; } w;
        w.s[0] = f2b(a.x); w.s[1] = f2b(a.y); w.s[2] = f2b(a.z); w.s[3] = f2b(a.w);
        w.s[4] = f2b(b.x); w.s[5] = f2b(b.y); w.s[6] = f2b(b.z); w.s[7] = f2b(b.w);
        *(bf16x8*)(dst + i) = w.v;
        return;
    }

    const int n0 = blockIdx.x * 64, c0 = blockIdx.y * 64, b = blockIdx.z;
    const int n2 = t >> 3, q = t & 7;   // row-pair 0..31, col-octet 0..7

    const float* src = u + ((long long)(b * NTOT + n0 + 2 * n2)) * CC + c0 + q * 8;
    const float4 a0 = *(const float4*)src;
    const float4 a1 = *(const float4*)(src + 4);
    const float4 b0 = *(const float4*)(src + CC);
    const float4 b1 = *(const float4*)(src + CC + 4);

    u16 h0[8], h1[8];
    h0[0]=f2b(a0.x); h0[1]=f2b(a0.y); h0[2]=f2b(a0.z); h0[3]=f2b(a0.w);
    h0[4]=f2b(a1.x); h0[5]=f2b(a1.y); h0[6]=f2b(a1.z); h0[7]=f2b(a1.w);
    h1[0]=f2b(b0.x); h1[1]=f2b(b0.y); h1[2]=f2b(b0.z); h1[3]=f2b(b0.w);
    h1[4]=f2b(b1.x); h1[5]=f2b(b1.y); h1[6]=f2b(b1.z); h1[7]=f2b(b1.w);

    {   // u_bf rows (coalesced 16B stores)
        union { bf16x8 v; u16 s[8]; } p0, p1;
#pragma unroll
        for (int k = 0; k < 8; k++) { p0.s[k] = h0[k]; p1.s[k] = h1[k]; }
        u16* dst = u_bf + ((long long)(b * NTOT + n0 + 2 * n2)) * CC + c0 + q * 8;
        *(bf16x8*)dst = p0.v;
        *(bf16x8*)(dst + CC) = p1.v;
    }
    {   // LDS: vertical pair-pack, octet XOR-swizzled by n2>>3
        u32 pk[8];
#pragma unroll
        for (int k = 0; k < 8; k++) pk[k] = (u32)h0[k] | ((u32)h1[k] << 16);
        u32* dl = &LA[n2][(q ^ (n2 >> 3)) * 8];
        u32x4 lo, hi;
        lo[0]=pk[0]; lo[1]=pk[1]; lo[2]=pk[2]; lo[3]=pk[3];
        hi[0]=pk[4]; hi[1]=pk[5]; hi[2]=pk[6]; hi[3]=pk[7];
        *(u32x4*)dl = lo;
        *(u32x4*)(dl + 4) = hi;
    }
    __syncthreads();
    {   // read 8 row-pairs at one column -> 16 consecutive n of uT row c
        const int wv = t >> 6, l = t & 63;
        const int c = wv * 16 + (l >> 2);
        const int g = l & 3;
        const int cs = (c & 7) + ((c >> 3) ^ g) * 8;
        u32 o[8];
#pragma unroll
        for (int k = 0; k < 8; k++) o[k] = LA[g * 8 + k][cs];
        u32x4 lo, hi;
        lo[0]=o[0]; lo[1]=o[1]; lo[2]=o[2]; lo[3]=o[3];
        hi[0]=o[4]; hi[1]=o[5]; hi[2]=o[6]; hi[3]=o[7];
        u16* dT = uT + ((long long)(b * CC + c0 + c)) * NTOT + n0 + g * 16;
        *(u32x4*)dT = lo;
        *(u32x4*)(dT + 8) = hi;
    }
}

// ---------------------------------------------------------------------------
// ggemm v2: Gp[z][i][j] = sum_{n in chunk ck} uT[b][i][n]*uT[b][j][n],
// z = b*32+ck (K-chunk 512). Single shared 256x32 LDS tile (A==B), 512 thr,
// 8 waves 4x2, 256x256 output. Emits per-chunk column sums suP. grid (128).
// ---------------------------------------------------------------------------
__global__ __launch_bounds__(512) void ggemm(
    const u16* __restrict__ uT, float* __restrict__ Gp, float* __restrict__ suP)
{
    __shared__ u16 Ts[256 * 32];   // 16 KB
    const int z = blockIdx.x, b = z >> 5, ck = z & 31;
    const u16* base = uT + (long long)b * CC * NTOT + ck * 512;
    const int t = threadIdx.x, w = t >> 6, l = t & 63;
    const int wy = w >> 1, wx = w & 1;
    const int r16 = l & 15, quad = l >> 4;
    const int srow = w * 16 + (l >> 2), scol = (l & 3) * 8;

    f32x4 acc[4][8] = {};
    float su = 0.f;

    for (int kk = 0; kk < 512; kk += 32) {
#pragma unroll
        for (int s = 0; s < 2; s++)
            GLD(base + (long long)(s * 128 + srow) * NTOT + kk + scol,
                Ts + s * 4096 + w * 512);
        __syncthreads();

        if (t < 256) {
            const u16* rw = Ts + t * 32;
            float s1 = 0.f;
#pragma unroll
            for (int k8 = 0; k8 < 4; k8++) {
                bf16x8 rv = *(const bf16x8*)(rw + k8 * 8);
#pragma unroll
                for (int k = 0; k < 8; k++) s1 += b2f((u16)rv[k]);
            }
            su += s1;
        }
        bf16x8 a[4], bb[8];
#pragma unroll
        for (int i = 0; i < 4; i++)
            a[i] = *(const bf16x8*)(Ts + (wy * 64 + 16 * i + r16) * 32 + quad * 8);
#pragma unroll
        for (int j = 0; j < 8; j++)
            bb[j] = *(const bf16x8*)(Ts + (wx * 128 + 16 * j + r16) * 32 + quad * 8);
#pragma unroll
        for (int i = 0; i < 4; i++)
#pragma unroll
            for (int j = 0; j < 8; j++)
                acc[i][j] = MFMA(a[i], bb[j], acc[i][j]);
        __syncthreads();
    }

    float* Cp = Gp + (long long)z * 65536;
#pragma unroll
    for (int i = 0; i < 4; i++)
#pragma unroll
        for (int j = 0; j < 8; j++)
#pragma unroll
            for (int rr = 0; rr < 4; rr++)
                Cp[(wy * 64 + 16 * i + quad * 4 + rr) * 256 + wx * 128 + 16 * j + r16]
                    = acc[i][j][rr];
    if (t < 256) suP[z * 256 + t] = su;
}

// ---------------------------------------------------------------------------
// gred v2: Gb[b][i][j] = bf16(sum_ck Gp), f32x4 per thread (4 cols).
// grid (64, 4), 256 thr; block x==0 also reduces suP -> su.
// ---------------------------------------------------------------------------
__global__ __launch_bounds__(256) void gred(
    const float* __restrict__ Gp, const float* __restrict__ suP,
    u16* __restrict__ Gb, float* __restrict__ su)
{
    const int b = blockIdx.y, t = threadIdx.x;
    const int row = blockIdx.x * 4 + (t >> 6);
    const int col = (t & 63) * 4;
    const float* p = Gp + (long long)(b * 32) * 65536 + row * 256 + col;
    f32x4 s = {};
#pragma unroll
    for (int ck = 0; ck < 32; ck++) {
        f32x4 v = *(const f32x4*)(p + (long long)ck * 65536);
        s[0] += v[0]; s[1] += v[1]; s[2] += v[2]; s[3] += v[3];
    }
    union { u16x4 v; u16 q[4]; } pk;
#pragma unroll
    for (int k = 0; k < 4; k++) pk.q[k] = f2b(s[k]);
    *(u16x4*)(Gb + (long long)b * 65536 + row * 256 + col) = pk.v;

    if (blockIdx.x == 0) {
        float s2 = 0.f;
#pragma unroll
        for (int ck = 0; ck < 32; ck++) s2 += suP[(b * 32 + ck) * 256 + t];
        su[b * 256 + t] = s2;
    }
}

// ---------------------------------------------------------------------------
// midend (proven r5): per (b,h): Pk/Pv = W_h*G (MFMA), stats, S=Pk*Wv^T,
// kv = rk rv (S/N - mk mv), Zt[c][h*64+e] = sum_d Wq[hd,c] kv[d,e].
// ---------------------------------------------------------------------------
__global__ __launch_bounds__(256) void midend(
    const u16* __restrict__ Gb, const float* __restrict__ su,
    const u16* __restrict__ Wk_b, const u16* __restrict__ Wv_b,
    const u16* __restrict__ Wq_b, u16* __restrict__ Zt)
{
    __shared__ u16 pool[20480];   // 40 KB
    __shared__ float e2kL[64], e2vL[64], mkL[64], rkL[64], mvL[64], rvL[64];

    const int bx = blockIdx.x, b = bx >> 3, h = bx & 7;
    const int t = threadIdx.x, w = t >> 6, l = t & 63;
    const int r16 = l & 15, quad = l >> 4;

    const u16* WkH = Wk_b + (h * 64) * 256;
    const u16* WvH = Wv_b + (h * 64) * 256;
    const u16* GbB = Gb + (long long)b * 65536;

    if (t < 64) e2kL[t] = 0.f;
    else if (t < 128) e2vL[t - 64] = 0.f;

    // ---- P-phase ----
    f32x4 acck[4][4] = {}, accv[4][4] = {};
    for (int ch = 0; ch < 8; ch++) {
        const int kk = ch * 32 + quad * 8;
        bf16x8 ak[4], av[4], bg[4];
#pragma unroll
        for (int i = 0; i < 4; i++) {
            ak[i] = *(const bf16x8*)(WkH + (16 * i + r16) * 256 + kk);
            av[i] = *(const bf16x8*)(WvH + (16 * i + r16) * 256 + kk);
        }
#pragma unroll
        for (int j = 0; j < 4; j++)
            bg[j] = *(const bf16x8*)(GbB + (w * 64 + 16 * j + r16) * 256 + kk);
#pragma unroll
        for (int i = 0; i < 4; i++)
#pragma unroll
            for (int j = 0; j < 4; j++) {
                acck[i][j] = MFMA(ak[i], bg[j], acck[i][j]);
                accv[i][j] = MFMA(av[i], bg[j], accv[i][j]);
            }
    }
    __syncthreads();

    // ---- PkL + e2 partials ----
    u16* PkL = pool;
#pragma unroll
    for (int i = 0; i < 4; i++) {
#pragma unroll
        for (int rr = 0; rr < 4; rr++) {
            const int a = 16 * i + quad * 4 + rr;
            float e2k = 0.f, e2v = 0.f;
#pragma unroll
            for (int jt = 0; jt < 4; jt++) {
                const int j = w * 64 + 16 * jt + r16;
                PkL[(j >> 5) * 2048 + a * 32 + (j & 31)] = f2b(acck[i][jt][rr]);
                e2k += acck[i][jt][rr] * b2f(WkH[a * 256 + j]);
                e2v += accv[i][jt][rr] * b2f(WvH[a * 256 + j]);
            }
            atomicAdd(&e2kL[a], e2k);
            atomicAdd(&e2vL[a], e2v);
        }
    }
    __syncthreads();

    // ---- stats ----
    if (t < 128) {
        const int a = t & 63;
        const u16* Wrow = (t < 64) ? (WkH + a * 256) : (WvH + a * 256);
        const float* suB = su + b * 256;
        float m = 0.f;
        for (int c8 = 0; c8 < 32; c8++) {
            bf16x8 wr = *(const bf16x8*)(Wrow + c8 * 8);
#pragma unroll
            for (int k = 0; k < 8; k++) m += b2f((u16)wr[k]) * suB[c8 * 8 + k];
        }
        m *= (1.0f / NTOT);
        const float e2 = ((t < 64) ? e2kL[a] : e2vL[a]) * (1.0f / NTOT);
        const float r = rsqrtf(e2 - m * m + 1e-5f);
        if (t < 64) { mkL[a] = m; rkL[a] = r; }
        else        { mvL[a] = m; rvL[a] = r; }
    }
    __syncthreads();

    // ---- S-phase ----
    const int mh = (w >> 1) * 32, nh = (w & 1) * 32;
    float mkR[2][4], rkR[2][4], mvR[2], rvR[2];
#pragma unroll
    for (int i = 0; i < 2; i++)
#pragma unroll
        for (int rr = 0; rr < 4; rr++) {
            mkR[i][rr] = mkL[mh + 16 * i + quad * 4 + rr];
            rkR[i][rr] = rkL[mh + 16 * i + quad * 4 + rr];
        }
#pragma unroll
    for (int j = 0; j < 2; j++) {
        mvR[j] = mvL[nh + 16 * j + r16];
        rvR[j] = rvL[nh + 16 * j + r16];
    }

    f32x4 accs[2][2] = {};
    for (int ch = 0; ch < 8; ch++) {
        const int ko = quad * 8;
        bf16x8 ap[2], bv[2];
#pragma unroll
        for (int i = 0; i < 2; i++)
            ap[i] = *(const bf16x8*)(PkL + ch * 2048 + (mh + 16 * i + r16) * 32 + ko);
#pragma unroll
        for (int j = 0; j < 2; j++)
            bv[j] = *(const bf16x8*)(WvH + (nh + 16 * j + r16) * 256 + ch * 32 + ko);
#pragma unroll
        for (int i = 0; i < 2; i++)
#pragma unroll
            for (int j = 0; j < 2; j++)
                accs[i][j] = MFMA(ap[i], bv[j], accs[i][j]);
    }
    __syncthreads();

    // ---- kv -> kvTL; WqTL ----
    u16* kvTL = pool;            // 8 KB
    u16* WqTL = pool + 4096;     // 32 KB
#pragma unroll
    for (int i = 0; i < 2; i++)
#pragma unroll
        for (int j = 0; j < 2; j++)
#pragma unroll
            for (int rr = 0; rr < 4; rr++) {
                const int d = mh + 16 * i + quad * 4 + rr;
                const int e = nh + 16 * j + r16;
                const float kv = rkR[i][rr] * rvR[j] *
                    (accs[i][j][rr] * (1.0f / NTOT) - mkR[i][rr] * mvR[j]);
                kvTL[(d >> 5) * 2048 + e * 32 + (d & 31)] = f2b(kv);
            }
    {
        const int d = t >> 2, q = t & 3;
        const u16* Wrow = Wq_b + (h * 64 + d) * 256 + q * 64;
#pragma unroll
        for (int s = 0; s < 8; s++) {
            bf16x8 raw = *(const bf16x8*)(Wrow + s * 8);
#pragma unroll
            for (int k = 0; k < 8; k++) {
                const int c = q * 64 + s * 8 + k;
                WqTL[(d >> 5) * 8192 + c * 32 + (d & 31)] = (u16)raw[k];
            }
        }
    }
    __syncthreads();

    // ---- Y-phase ----
    f32x4 accy[4][4] = {};
#pragma unroll
    for (int ch = 0; ch < 2; ch++) {
        const int ko = quad * 8;
        bf16x8 akv[4], bq[4];
#pragma unroll
        for (int i = 0; i < 4; i++)
            akv[i] = *(const bf16x8*)(kvTL + ch * 2048 + (16 * i + r16) * 32 + ko);
#pragma unroll
        for (int j = 0; j < 4; j++)
            bq[j] = *(const bf16x8*)(WqTL + ch * 8192 + (w * 64 + 16 * j + r16) * 32 + ko);
#pragma unroll
        for (int i = 0; i < 4; i++)
#pragma unroll
            for (int j = 0; j < 4; j++)
                accy[i][j] = MFMA(akv[i], bq[j], accy[i][j]);
    }
#pragma unroll
    for (int i = 0; i < 4; i++)
#pragma unroll
        for (int j = 0; j < 4; j++) {
            const int c = w * 64 + 16 * j + r16;
            const int e0 = 16 * i + quad * 4;
            union { u16x4 v; u16 s[4]; } pk;
#pragma unroll
            for (int rr = 0; rr < 4; rr++) pk.s[rr] = f2b(accy[i][j][rr]);
            *(u16x4*)(Zt + ((long long)(b * 256 + c)) * 512 + h * 64 + e0) = pk.v;
        }
}

// ---------------------------------------------------------------------------
// gemm_bt (proven): C[m,n] = sum_k A[m,k]*Bm[n,k] (+bias[n]).
// ---------------------------------------------------------------------------
template <typename CT>
__global__ __launch_bounds__(256) void gemm_bt(
    const u16* __restrict__ A, const u16* __restrict__ Bm,
    CT* __restrict__ C, const float* __restrict__ bias,
    int K, int lda, int ldc,
    long long aStride, long long bStride, long long cStride)
{
    __shared__ u16 As[128 * 32];
    __shared__ u16 Bs[128 * 32];

    const int bz = blockIdx.z;
    A  += (long long)bz * aStride;
    Bm += (long long)bz * bStride;
    C  += (long long)bz * cStride;

    const int m0 = blockIdx.x * 128;
    const int n0 = blockIdx.y * 128;
    const int t  = threadIdx.x;
    const int wv = t >> 6, l = t & 63;
    const int wy = wv >> 1, wx = wv & 1;
    const int r16  = l & 15;
    const int quad = l >> 4;
    const int srow = wv * 16 + (l >> 2);
    const int scol = (l & 3) * 8;

    f32x4 acc[4][4] = {};

    for (int kk = 0; kk < K; kk += 32) {
#pragma unroll
        for (int s = 0; s < 2; s++) {
            GLD(A + (long long)(m0 + s * 64 + srow) * lda + kk + scol,
                As + s * 2048 + wv * 512);
            GLD(Bm + (long long)(n0 + s * 64 + srow) * K + kk + scol,
                Bs + s * 2048 + wv * 512);
        }
        __syncthreads();

        bf16x8 a[4], b[4];
#pragma unroll
        for (int i = 0; i < 4; i++)
            a[i] = *(const bf16x8*)(As + (wy * 64 + 16 * i + r16) * 32 + quad * 8);
#pragma unroll
        for (int j = 0; j < 4; j++)
            b[j] = *(const bf16x8*)(Bs + (wx * 64 + 16 * j + r16) * 32 + quad * 8);
#pragma unroll
        for (int i = 0; i < 4; i++)
#pragma unroll
            for (int j = 0; j < 4; j++)
                acc[i][j] = MFMA(a[i], b[j], acc[i][j]);
        __syncthreads();
    }

#pragma unroll
    for (int j = 0; j < 4; j++) {
        const int col = n0 + wx * 64 + 16 * j + r16;
        const float bv = bias ? bias[col] : 0.0f;
#pragma unroll
        for (int i = 0; i < 4; i++) {
#pragma unroll
            for (int r = 0; r < 4; r++) {
                const int row = m0 + wy * 64 + 16 * i + quad * 4 + r;
                const float v = acc[i][j][r] + bv;
                if constexpr (sizeof(CT) == 2) C[(long long)row * ldc + col] = f2b(v);
                else                           C[(long long)row * ldc + col] = v;
            }
        }
    }
}

// ---------------------------------------------------------------------------
extern "C" void kernel_launch(void* const* d_in, const int* in_sizes, int n_in,
                              void* d_out, int out_size, void* d_ws, size_t ws_size,
                              hipStream_t stream)
{
    const float* u_src = (const float*)d_in[0];
    // d_in[1] = pos_src (unused)
    const float* Wq = (const float*)d_in[2];
    const float* Wk = (const float*)d_in[3];
    const float* Wv = (const float*)d_in[4];
    const float* Wo = (const float*)d_in[5];
    const float* bo = (const float*)d_in[6];
    float* out = (float*)d_out;

    char* ws = (char*)d_ws;
    size_t off = 0;
    u16*  u_bf = (u16*)(ws + off);  off += 33554432;   // [4][16384][256] bf16
    u16*  uT   = (u16*)(ws + off);  off += 33554432;   // [4][256][16384] bf16
    float* Gp  = (float*)(ws + off); off += 33554432;  // [128][256][256] f32
    float* suP = (float*)(ws + off); off += 131072;    // [128][256] f32
    u16*  Gb   = (u16*)(ws + off);  off += 524288;     // [4][256][256] bf16
    u16*  Wq_b = (u16*)(ws + off);  off += 262144;
    u16*  Wk_b = (u16*)(ws + off);  off += 262144;
    u16*  Wv_b = (u16*)(ws + off);  off += 262144;
    u16*  Wo_b = (u16*)(ws + off);  off += 262144;     // [256][512] bf16
    float* su  = (float*)(ws + off); off += 4096;      // [4][256] f32
    u16*  Zt   = (u16*)(ws + off);  off += 1048576;    // [4][256][512] bf16
    u16*  Ft   = (u16*)(ws + off);  off += 524288;     // [4][256][256] bf16

    const dim3 blk(256);

    // u -> u_bf + uT, weights -> bf16 (fused y==4 plane)
    prep_u<<<dim3(NTOT / 64, 5, BB), blk, 0, stream>>>(
        u_src, u_bf, uT, Wq, Wk, Wv, Wo, Wq_b, Wk_b, Wv_b, Wo_b);

    // G = uT uT^T (split-K 32, shared operand) + su partials
    ggemm<<<dim3(BB * 32), dim3(512), 0, stream>>>(uT, Gp, suP);
    gred<<<dim3(64, BB), blk, 0, stream>>>(Gp, suP, Gb, su);

    // P/stats/S/kv/Zt fused
    midend<<<dim3(BB * HH), blk, 0, stream>>>(Gb, su, Wk_b, Wv_b, Wq_b, Zt);

    // Ft[b] = Wo Zt_b^T : [256x512]x[512x256]
    gemm_bt<u16><<<dim3(2, 2, BB), blk, 0, stream>>>(
        Wo_b, Zt, Ft, nullptr, 512, 512, 256, 0, 131072, 65536);

    // out = u_bf Ft^T + bo : [16384x256]x[256x256] per b
    gemm_bt<float><<<dim3(128, 2, BB), blk, 0, stream>>>(
        u_bf, Ft, out, bo, 256, 256, 256,
        (long long)NTOT * CC, 65536, (long long)NTOT * OUTC);
}

// Round 8
// 223.278 us; speedup vs baseline: 3.0200x; 1.1344x over previous
//
#include <hip/hip_runtime.h>
#include <hip/hip_bf16.h>

// Problem constants (from reference setup_inputs)
#define BB    4
#define NTOT  16384
#define CC    256
#define HH    8
#define DD    64
#define HD    512
#define OUTC  256

typedef unsigned short u16;
typedef unsigned int u32;
typedef __attribute__((ext_vector_type(8))) short bf16x8;   // 8 bf16 in 4 VGPRs
typedef __attribute__((ext_vector_type(4))) float f32x4;
typedef __attribute__((ext_vector_type(4))) short u16x4;
typedef __attribute__((ext_vector_type(4))) u32 u32x4;

__device__ __forceinline__ float b2f(u16 u) {
    union { float f; u32 i; } x; x.i = ((u32)u) << 16; return x.f;
}
__device__ __forceinline__ u16 f2b(float f) {
    union { float f; u32 i; } x; x.f = f;
    u32 r = x.i + 0x7fffu + ((x.i >> 16) & 1u);   // round-to-nearest-even
    return (u16)(r >> 16);
}

#define GLD(gp, lp) __builtin_amdgcn_global_load_lds( \
    (const __attribute__((address_space(1))) void*)(gp), \
    (__attribute__((address_space(3))) void*)(lp), 16, 0, 0)

#define MFMA(a, b, c) __builtin_amdgcn_mfma_f32_16x16x32_bf16((a), (b), (c), 0, 0, 0)

// ---------------------------------------------------------------------------
// wcvt: 4 weight matrices (each 131072 f32) -> bf16. grid (64, 1, 4).
// ---------------------------------------------------------------------------
__global__ __launch_bounds__(256) void wcvt(
    const float* __restrict__ Wq, const float* __restrict__ Wk,
    const float* __restrict__ Wv, const float* __restrict__ Wo,
    u16* __restrict__ q, u16* __restrict__ k,
    u16* __restrict__ v, u16* __restrict__ o)
{
    const int z = blockIdx.z;
    const float* src = z == 0 ? Wq : z == 1 ? Wk : z == 2 ? Wv : Wo;
    u16* dst = z == 0 ? q : z == 1 ? k : z == 2 ? v : o;
    const int i = (blockIdx.x * 256 + threadIdx.x) * 8;
    const float4 a = *(const float4*)(src + i);
    const float4 b = *(const float4*)(src + i + 4);
    union { bf16x8 v; u16 s[8]; } w;
    w.s[0] = f2b(a.x); w.s[1] = f2b(a.y); w.s[2] = f2b(a.z); w.s[3] = f2b(a.w);
    w.s[4] = f2b(b.x); w.s[5] = f2b(b.y); w.s[6] = f2b(b.z); w.s[7] = f2b(b.w);
    *(bf16x8*)(dst + i) = w.v;
}

// ---------------------------------------------------------------------------
// ggemm v3: Gp[z][i][j] = sum_{n in chunk ck} bf16(u[b][n][i])*bf16(u[b][n][j])
// z = b*64+ck, chunk = 256 n, 8 k-steps of 32 n. Reads u f32 DIRECTLY,
// converts + transposes in LDS staging (no uT buffer).
// Ts layout: u32 pair-pack (two consecutive n per u32), Ts[p*290 + 9*(c>>3)
// + (c&7)]: 9-stride octets -> conflict-free scatter writes; 290 % 32 == 2
// -> <=2-way fragment reads (free). 512 thr (8 waves 4x2), 256x256 output.
// Also emits per-chunk column sums suP[z][c]. grid (256).
// ---------------------------------------------------------------------------
__global__ __launch_bounds__(512) void ggemm(
    const float* __restrict__ u, float* __restrict__ Gp, float* __restrict__ suP)
{
    __shared__ u32 Ts[16 * 290];   // 18.6 KB
    const int z = blockIdx.x, b = z >> 6, ck = z & 63;
    const float* base = u + (long long)b * NTOT * CC + (long long)ck * 256 * CC;
    const int t = threadIdx.x, w = t >> 6, l = t & 63;
    const int wy = w >> 1, wx = w & 1;
    const int r16 = l & 15, quad = l >> 4;
    const int sp = t >> 5;          // n-pair 0..15
    const int sq = t & 31;          // c-octet 0..31

    // fragment column-swizzle bases
    const int csa0 = 9 * ((wy * 64 + r16) >> 3) + (r16 & 7);     // + 18*i
    const int csb0 = 9 * ((wx * 128 + r16) >> 3) + (r16 & 7);    // + 18*j
    const int pr0 = 4 * quad * 290;

    f32x4 acc[4][8] = {};
    float su = 0.f;

    float4 a0, a1, b0, b1;
    {
        const float* src = base + (long long)(2 * sp) * CC + sq * 8;
        a0 = *(const float4*)src;       a1 = *(const float4*)(src + 4);
        b0 = *(const float4*)(src + CC); b1 = *(const float4*)(src + CC + 4);
    }

    for (int it = 0; it < 8; it++) {
        __syncthreads();   // prev iter's LDS reads complete (no-op first iter)
        {   // cvt + pair-pack + scatter-write (conflict-free via 9-stride)
            u32 pk[8];
            pk[0] = (u32)(u16)f2b(a0.x) | ((u32)f2b(b0.x) << 16);
            pk[1] = (u32)(u16)f2b(a0.y) | ((u32)f2b(b0.y) << 16);
            pk[2] = (u32)(u16)f2b(a0.z) | ((u32)f2b(b0.z) << 16);
            pk[3] = (u32)(u16)f2b(a0.w) | ((u32)f2b(b0.w) << 16);
            pk[4] = (u32)(u16)f2b(a1.x) | ((u32)f2b(b1.x) << 16);
            pk[5] = (u32)(u16)f2b(a1.y) | ((u32)f2b(b1.y) << 16);
            pk[6] = (u32)(u16)f2b(a1.z) | ((u32)f2b(b1.z) << 16);
            pk[7] = (u32)(u16)f2b(a1.w) | ((u32)f2b(b1.w) << 16);
            u32* dst = Ts + sp * 290 + 9 * sq;
#pragma unroll
            for (int k = 0; k < 8; k++) dst[k] = pk[k];
        }
        if (it < 7) {   // prefetch next 32-n slab (overlaps barrier+compute)
            const float* src = base + (long long)((it + 1) * 32 + 2 * sp) * CC + sq * 8;
            a0 = *(const float4*)src;       a1 = *(const float4*)(src + 4);
            b0 = *(const float4*)(src + CC); b1 = *(const float4*)(src + CC + 4);
        }
        __syncthreads();

        if (t < 256) {   // su partial for channel c = t
            const int cs = 9 * (t >> 3) + (t & 7);
            float s1 = 0.f;
#pragma unroll
            for (int p = 0; p < 16; p++) {
                u32 v = Ts[p * 290 + cs];
                s1 += b2f((u16)(v & 0xffff)) + b2f((u16)(v >> 16));
            }
            su += s1;
        }

        bf16x8 a[4], bb[8];
#pragma unroll
        for (int i = 0; i < 4; i++) {
            const int cs = csa0 + 18 * i;
            union { u32x4 u4; bf16x8 h; } f;
            f.u4[0] = Ts[pr0 + cs];       f.u4[1] = Ts[pr0 + 290 + cs];
            f.u4[2] = Ts[pr0 + 580 + cs]; f.u4[3] = Ts[pr0 + 870 + cs];
            a[i] = f.h;
        }
#pragma unroll
        for (int j = 0; j < 8; j++) {
            const int cs = csb0 + 18 * j;
            union { u32x4 u4; bf16x8 h; } f;
            f.u4[0] = Ts[pr0 + cs];       f.u4[1] = Ts[pr0 + 290 + cs];
            f.u4[2] = Ts[pr0 + 580 + cs]; f.u4[3] = Ts[pr0 + 870 + cs];
            bb[j] = f.h;
        }
#pragma unroll
        for (int i = 0; i < 4; i++)
#pragma unroll
            for (int j = 0; j < 8; j++)
                acc[i][j] = MFMA(a[i], bb[j], acc[i][j]);
    }

    float* Cp = Gp + (long long)z * 65536;
#pragma unroll
    for (int i = 0; i < 4; i++)
#pragma unroll
        for (int j = 0; j < 8; j++)
#pragma unroll
            for (int rr = 0; rr < 4; rr++)
                Cp[(wy * 64 + 16 * i + quad * 4 + rr) * 256 + wx * 128 + 16 * j + r16]
                    = acc[i][j][rr];
    if (t < 256) suP[z * 256 + t] = su;
}

// ---------------------------------------------------------------------------
// gred: Gb[b][i][j] = bf16(sum_{ck<64} Gp), f32x4 per thread (4 cols).
// grid (64, 4), 256 thr; block x==0 also reduces suP -> su.
// ---------------------------------------------------------------------------
__global__ __launch_bounds__(256) void gred(
    const float* __restrict__ Gp, const float* __restrict__ suP,
    u16* __restrict__ Gb, float* __restrict__ su)
{
    const int b = blockIdx.y, t = threadIdx.x;
    const int row = blockIdx.x * 4 + (t >> 6);
    const int col = (t & 63) * 4;
    const float* p = Gp + (long long)(b * 64) * 65536 + row * 256 + col;
    f32x4 s = {};
#pragma unroll
    for (int ck = 0; ck < 64; ck++) {
        f32x4 v = *(const f32x4*)(p + (long long)ck * 65536);
        s[0] += v[0]; s[1] += v[1]; s[2] += v[2]; s[3] += v[3];
    }
    union { u16x4 v; u16 q[4]; } pk;
#pragma unroll
    for (int k = 0; k < 4; k++) pk.q[k] = f2b(s[k]);
    *(u16x4*)(Gb + (long long)b * 65536 + row * 256 + col) = pk.v;

    if (blockIdx.x == 0) {
        float s2 = 0.f;
#pragma unroll
        for (int ck = 0; ck < 64; ck++) s2 += suP[(b * 64 + ck) * 256 + t];
        su[b * 256 + t] = s2;
    }
}

// ---------------------------------------------------------------------------
// midend (proven r5): per (b,h): Pk/Pv = W_h*G (MFMA), stats, S=Pk*Wv^T,
// kv = rk rv (S/N - mk mv), Zt[c][h*64+e] = sum_d Wq[hd,c] kv[d,e].
// ---------------------------------------------------------------------------
__global__ __launch_bounds__(256) void midend(
    const u16* __restrict__ Gb, const float* __restrict__ su,
    const u16* __restrict__ Wk_b, const u16* __restrict__ Wv_b,
    const u16* __restrict__ Wq_b, u16* __restrict__ Zt)
{
    __shared__ u16 pool[20480];   // 40 KB
    __shared__ float e2kL[64], e2vL[64], mkL[64], rkL[64], mvL[64], rvL[64];

    const int bx = blockIdx.x, b = bx >> 3, h = bx & 7;
    const int t = threadIdx.x, w = t >> 6, l = t & 63;
    const int r16 = l & 15, quad = l >> 4;

    const u16* WkH = Wk_b + (h * 64) * 256;
    const u16* WvH = Wv_b + (h * 64) * 256;
    const u16* GbB = Gb + (long long)b * 65536;

    if (t < 64) e2kL[t] = 0.f;
    else if (t < 128) e2vL[t - 64] = 0.f;

    // ---- P-phase ----
    f32x4 acck[4][4] = {}, accv[4][4] = {};
    for (int ch = 0; ch < 8; ch++) {
        const int kk = ch * 32 + quad * 8;
        bf16x8 ak[4], av[4], bg[4];
#pragma unroll
        for (int i = 0; i < 4; i++) {
            ak[i] = *(const bf16x8*)(WkH + (16 * i + r16) * 256 + kk);
            av[i] = *(const bf16x8*)(WvH + (16 * i + r16) * 256 + kk);
        }
#pragma unroll
        for (int j = 0; j < 4; j++)
            bg[j] = *(const bf16x8*)(GbB + (w * 64 + 16 * j + r16) * 256 + kk);
#pragma unroll
        for (int i = 0; i < 4; i++)
#pragma unroll
            for (int j = 0; j < 4; j++) {
                acck[i][j] = MFMA(ak[i], bg[j], acck[i][j]);
                accv[i][j] = MFMA(av[i], bg[j], accv[i][j]);
            }
    }
    __syncthreads();

    // ---- PkL + e2 partials ----
    u16* PkL = pool;
#pragma unroll
    for (int i = 0; i < 4; i++) {
#pragma unroll
        for (int rr = 0; rr < 4; rr++) {
            const int a = 16 * i + quad * 4 + rr;
            float e2k = 0.f, e2v = 0.f;
#pragma unroll
            for (int jt = 0; jt < 4; jt++) {
                const int j = w * 64 + 16 * jt + r16;
                PkL[(j >> 5) * 2048 + a * 32 + (j & 31)] = f2b(acck[i][jt][rr]);
                e2k += acck[i][jt][rr] * b2f(WkH[a * 256 + j]);
                e2v += accv[i][jt][rr] * b2f(WvH[a * 256 + j]);
            }
            atomicAdd(&e2kL[a], e2k);
            atomicAdd(&e2vL[a], e2v);
        }
    }
    __syncthreads();

    // ---- stats ----
    if (t < 128) {
        const int a = t & 63;
        const u16* Wrow = (t < 64) ? (WkH + a * 256) : (WvH + a * 256);
        const float* suB = su + b * 256;
        float m = 0.f;
        for (int c8 = 0; c8 < 32; c8++) {
            bf16x8 wr = *(const bf16x8*)(Wrow + c8 * 8);
#pragma unroll
            for (int k = 0; k < 8; k++) m += b2f((u16)wr[k]) * suB[c8 * 8 + k];
        }
        m *= (1.0f / NTOT);
        const float e2 = ((t < 64) ? e2kL[a] : e2vL[a]) * (1.0f / NTOT);
        const float r = rsqrtf(e2 - m * m + 1e-5f);
        if (t < 64) { mkL[a] = m; rkL[a] = r; }
        else        { mvL[a] = m; rvL[a] = r; }
    }
    __syncthreads();

    // ---- S-phase ----
    const int mh = (w >> 1) * 32, nh = (w & 1) * 32;
    float mkR[2][4], rkR[2][4], mvR[2], rvR[2];
#pragma unroll
    for (int i = 0; i < 2; i++)
#pragma unroll
        for (int rr = 0; rr < 4; rr++) {
            mkR[i][rr] = mkL[mh + 16 * i + quad * 4 + rr];
            rkR[i][rr] = rkL[mh + 16 * i + quad * 4 + rr];
        }
#pragma unroll
    for (int j = 0; j < 2; j++) {
        mvR[j] = mvL[nh + 16 * j + r16];
        rvR[j] = rvL[nh + 16 * j + r16];
    }

    f32x4 accs[2][2] = {};
    for (int ch = 0; ch < 8; ch++) {
        const int ko = quad * 8;
        bf16x8 ap[2], bv[2];
#pragma unroll
        for (int i = 0; i < 2; i++)
            ap[i] = *(const bf16x8*)(PkL + ch * 2048 + (mh + 16 * i + r16) * 32 + ko);
#pragma unroll
        for (int j = 0; j < 2; j++)
            bv[j] = *(const bf16x8*)(WvH + (nh + 16 * j + r16) * 256 + ch * 32 + ko);
#pragma unroll
        for (int i = 0; i < 2; i++)
#pragma unroll
            for (int j = 0; j < 2; j++)
                accs[i][j] = MFMA(ap[i], bv[j], accs[i][j]);
    }
    __syncthreads();

    // ---- kv -> kvTL; WqTL ----
    u16* kvTL = pool;            // 8 KB
    u16* WqTL = pool + 4096;     // 32 KB
#pragma unroll
    for (int i = 0; i < 2; i++)
#pragma unroll
        for (int j = 0; j < 2; j++)
#pragma unroll
            for (int rr = 0; rr < 4; rr++) {
                const int d = mh + 16 * i + quad * 4 + rr;
                const int e = nh + 16 * j + r16;
                const float kv = rkR[i][rr] * rvR[j] *
                    (accs[i][j][rr] * (1.0f / NTOT) - mkR[i][rr] * mvR[j]);
                kvTL[(d >> 5) * 2048 + e * 32 + (d & 31)] = f2b(kv);
            }
    {
        const int d = t >> 2, q = t & 3;
        const u16* Wrow = Wq_b + (h * 64 + d) * 256 + q * 64;
#pragma unroll
        for (int s = 0; s < 8; s++) {
            bf16x8 raw = *(const bf16x8*)(Wrow + s * 8);
#pragma unroll
            for (int k = 0; k < 8; k++) {
                const int c = q * 64 + s * 8 + k;
                WqTL[(d >> 5) * 8192 + c * 32 + (d & 31)] = (u16)raw[k];
            }
        }
    }
    __syncthreads();

    // ---- Y-phase ----
    f32x4 accy[4][4] = {};
#pragma unroll
    for (int ch = 0; ch < 2; ch++) {
        const int ko = quad * 8;
        bf16x8 akv[4], bq[4];
#pragma unroll
        for (int i = 0; i < 4; i++)
            akv[i] = *(const bf16x8*)(kvTL + ch * 2048 + (16 * i + r16) * 32 + ko);
#pragma unroll
        for (int j = 0; j < 4; j++)
            bq[j] = *(const bf16x8*)(WqTL + ch * 8192 + (w * 64 + 16 * j + r16) * 32 + ko);
#pragma unroll
        for (int i = 0; i < 4; i++)
#pragma unroll
            for (int j = 0; j < 4; j++)
                accy[i][j] = MFMA(akv[i], bq[j], accy[i][j]);
    }
#pragma unroll
    for (int i = 0; i < 4; i++)
#pragma unroll
        for (int j = 0; j < 4; j++) {
            const int c = w * 64 + 16 * j + r16;
            const int e0 = 16 * i + quad * 4;
            union { u16x4 v; u16 s[4]; } pk;
#pragma unroll
            for (int rr = 0; rr < 4; rr++) pk.s[rr] = f2b(accy[i][j][rr]);
            *(u16x4*)(Zt + ((long long)(b * 256 + c)) * 512 + h * 64 + e0) = pk.v;
        }
}

// ---------------------------------------------------------------------------
// gemm_bt (proven): C[m,n] = sum_k A[m,k]*Bm[n,k] (+bias[n]); bf16 A,B.
// ---------------------------------------------------------------------------
template <typename CT>
__global__ __launch_bounds__(256) void gemm_bt(
    const u16* __restrict__ A, const u16* __restrict__ Bm,
    CT* __restrict__ C, const float* __restrict__ bias,
    int K, int lda, int ldc,
    long long aStride, long long bStride, long long cStride)
{
    __shared__ u16 As[128 * 32];
    __shared__ u16 Bs[128 * 32];

    const int bz = blockIdx.z;
    A  += (long long)bz * aStride;
    Bm += (long long)bz * bStride;
    C  += (long long)bz * cStride;

    const int m0 = blockIdx.x * 128;
    const int n0 = blockIdx.y * 128;
    const int t  = threadIdx.x;
    const int wv = t >> 6, l = t & 63;
    const int wy = wv >> 1, wx = wv & 1;
    const int r16  = l & 15;
    const int quad = l >> 4;
    const int srow = wv * 16 + (l >> 2);
    const int scol = (l & 3) * 8;

    f32x4 acc[4][4] = {};

    for (int kk = 0; kk < K; kk += 32) {
#pragma unroll
        for (int s = 0; s < 2; s++) {
            GLD(A + (long long)(m0 + s * 64 + srow) * lda + kk + scol,
                As + s * 2048 + wv * 512);
            GLD(Bm + (long long)(n0 + s * 64 + srow) * K + kk + scol,
                Bs + s * 2048 + wv * 512);
        }
        __syncthreads();

        bf16x8 a[4], b[4];
#pragma unroll
        for (int i = 0; i < 4; i++)
            a[i] = *(const bf16x8*)(As + (wy * 64 + 16 * i + r16) * 32 + quad * 8);
#pragma unroll
        for (int j = 0; j < 4; j++)
            b[j] = *(const bf16x8*)(Bs + (wx * 64 + 16 * j + r16) * 32 + quad * 8);
#pragma unroll
        for (int i = 0; i < 4; i++)
#pragma unroll
            for (int j = 0; j < 4; j++)
                acc[i][j] = MFMA(a[i], b[j], acc[i][j]);
        __syncthreads();
    }

#pragma unroll
    for (int j = 0; j < 4; j++) {
        const int col = n0 + wx * 64 + 16 * j + r16;
        const float bv = bias ? bias[col] : 0.0f;
#pragma unroll
        for (int i = 0; i < 4; i++) {
#pragma unroll
            for (int r = 0; r < 4; r++) {
                const int row = m0 + wy * 64 + 16 * i + quad * 4 + r;
                const float v = acc[i][j][r] + bv;
                if constexpr (sizeof(CT) == 2) C[(long long)row * ldc + col] = f2b(v);
                else                           C[(long long)row * ldc + col] = v;
            }
        }
    }
}

// ---------------------------------------------------------------------------
// gemm_uf32: out[n,o] = sum_c bf16(u[b][n][c]) * Ft[b][o][c] + bo[o], f32 out.
// A staged from f32 u with inline cvt (2x b128 LDS writes/thread); B (Ft)
// via proven GLD path. 128x128 tile, K=256, grid (128, 2, 4).
// ---------------------------------------------------------------------------
__global__ __launch_bounds__(256) void gemm_uf32(
    const float* __restrict__ uf, const u16* __restrict__ Ft,
    float* __restrict__ C, const float* __restrict__ bias)
{
    __shared__ u16 As[128 * 32];
    __shared__ u16 Bs[128 * 32];

    const int b = blockIdx.z;
    uf += (long long)b * NTOT * CC;
    const u16* Bm = Ft + (long long)b * 65536;
    C += (long long)b * NTOT * OUTC;

    const int m0 = blockIdx.x * 128;
    const int n0 = blockIdx.y * 128;
    const int t  = threadIdx.x;
    const int wv = t >> 6, l = t & 63;
    const int wy = wv >> 1, wx = wv & 1;
    const int r16  = l & 15;
    const int quad = l >> 4;
    const int srow = wv * 16 + (l >> 2);
    const int scol = (l & 3) * 8;
    const int ar = t >> 1, ah = t & 1;   // A-staging: row 0..127, 16-col half

    f32x4 acc[4][4] = {};

    for (int kk = 0; kk < 256; kk += 32) {
        {   // A: load f32, cvt, 2x b128 LDS writes
            const float* s = uf + (long long)(m0 + ar) * CC + kk + ah * 16;
            float4 v0 = *(const float4*)s;
            float4 v1 = *(const float4*)(s + 4);
            float4 v2 = *(const float4*)(s + 8);
            float4 v3 = *(const float4*)(s + 12);
            union { bf16x8 v; u16 q[8]; } p0, p1;
            p0.q[0]=f2b(v0.x); p0.q[1]=f2b(v0.y); p0.q[2]=f2b(v0.z); p0.q[3]=f2b(v0.w);
            p0.q[4]=f2b(v1.x); p0.q[5]=f2b(v1.y); p0.q[6]=f2b(v1.z); p0.q[7]=f2b(v1.w);
            p1.q[0]=f2b(v2.x); p1.q[1]=f2b(v2.y); p1.q[2]=f2b(v2.z); p1.q[3]=f2b(v2.w);
            p1.q[4]=f2b(v3.x); p1.q[5]=f2b(v3.y); p1.q[6]=f2b(v3.z); p1.q[7]=f2b(v3.w);
            u16* d = As + ar * 32 + ah * 16;
            *(bf16x8*)d = p0.v;
            *(bf16x8*)(d + 8) = p1.v;
        }
#pragma unroll
        for (int s = 0; s < 2; s++)
            GLD(Bm + (long long)(n0 + s * 64 + srow) * 256 + kk + scol,
                Bs + s * 2048 + wv * 512);
        __syncthreads();

        bf16x8 a[4], bb[4];
#pragma unroll
        for (int i = 0; i < 4; i++)
            a[i] = *(const bf16x8*)(As + (wy * 64 + 16 * i + r16) * 32 + quad * 8);
#pragma unroll
        for (int j = 0; j < 4; j++)
            bb[j] = *(const bf16x8*)(Bs + (wx * 64 + 16 * j + r16) * 32 + quad * 8);
#pragma unroll
        for (int i = 0; i < 4; i++)
#pragma unroll
            for (int j = 0; j < 4; j++)
                acc[i][j] = MFMA(a[i], bb[j], acc[i][j]);
        __syncthreads();
    }

#pragma unroll
    for (int j = 0; j < 4; j++) {
        const int col = n0 + wx * 64 + 16 * j + r16;
        const float bv = bias[col];
#pragma unroll
        for (int i = 0; i < 4; i++) {
#pragma unroll
            for (int r = 0; r < 4; r++) {
                const int row = m0 + wy * 64 + 16 * i + quad * 4 + r;
                C[(long long)row * OUTC + col] = acc[i][j][r] + bv;
            }
        }
    }
}

// ---------------------------------------------------------------------------
extern "C" void kernel_launch(void* const* d_in, const int* in_sizes, int n_in,
                              void* d_out, int out_size, void* d_ws, size_t ws_size,
                              hipStream_t stream)
{
    const float* u_src = (const float*)d_in[0];
    // d_in[1] = pos_src (unused)
    const float* Wq = (const float*)d_in[2];
    const float* Wk = (const float*)d_in[3];
    const float* Wv = (const float*)d_in[4];
    const float* Wo = (const float*)d_in[5];
    const float* bo = (const float*)d_in[6];
    float* out = (float*)d_out;

    char* ws = (char*)d_ws;
    size_t off = 0;
    float* Gp  = (float*)(ws + off); off += 67108864;  // [256][256][256] f32 partials (64 MB!)
    float* suP = (float*)(ws + off); off += 262144;    // [256][256] f32
    u16*  Gb   = (u16*)(ws + off);  off += 524288;     // [4][256][256] bf16
    u16*  Wq_b = (u16*)(ws + off);  off += 262144;
    u16*  Wk_b = (u16*)(ws + off);  off += 262144;
    u16*  Wv_b = (u16*)(ws + off);  off += 262144;
    u16*  Wo_b = (u16*)(ws + off);  off += 262144;     // [256][512] bf16
    float* su  = (float*)(ws + off); off += 4096;      // [4][256] f32
    u16*  Zt   = (u16*)(ws + off);  off += 1048576;    // [4][256][512] bf16
    u16*  Ft   = (u16*)(ws + off);  off += 524288;     // [4][256][256] bf16

    const dim3 blk(256);

    // weights -> bf16
    wcvt<<<dim3(64, 1, 4), blk, 0, stream>>>(Wq, Wk, Wv, Wo, Wq_b, Wk_b, Wv_b, Wo_b);

    // G partials directly from f32 u (cvt+transpose in staging) + su partials
    ggemm<<<dim3(BB * 64), dim3(512), 0, stream>>>(u_src, Gp, suP);
    gred<<<dim3(64, BB), blk, 0, stream>>>(Gp, suP, Gb, su);

    // P/stats/S/kv/Zt fused
    midend<<<dim3(BB * HH), blk, 0, stream>>>(Gb, su, Wk_b, Wv_b, Wq_b, Zt);

    // Ft[b] = Wo Zt_b^T : [256x512]x[512x256]
    gemm_bt<u16><<<dim3(2, 2, BB), blk, 0, stream>>>(
        Wo_b, Zt, Ft, nullptr, 512, 512, 256, 0, 131072, 65536);

    // out = u Ft^T + bo (A from f32 u, inline cvt)
    gemm_uf32<<<dim3(128, 2, BB), blk, 0, stream>>>(u_src, Ft, out, bo);
}